// Round 12
// baseline (735.826 us; speedup 1.0000x reference)
//
#include <hip/hip_runtime.h>
#include <hip/hip_bf16.h>
#include <math.h>
#include <type_traits>

// HGAT: 2-layer hypergraph attention. N nodes, M hyperedges, E incidence edges, D=128.
// R12 == R11 resubmit (container died before benching R11).
// R11: XCD column-sliced segA. R10's segA FETCH=180MB ~= 8 XCDs x 25.6MB h (each private
// L2 re-fetches the whole array). Slice D=128 into 8x16-col slices, block id = g*8+slice
// so slice s pins to XCD s (consecutive ids round-robin XCDs) -> per-XCD h slice 3.2MB
// L2-resident. Wave = 32 edge-slots x 2 lanes. ea -> k_ea; per-edge exp -> wn[] (k_wnode).
// Also: layer-1 sm2 eliminated (segB<1> unscaled + S2 partials; fc2 scales input by 1/S2);
// layer-2 sm2 -> CSR-based k_sm2c. Scatter v3 (R8), MFMA fc (R4), bf16 rows (R3).

typedef unsigned int u32;
typedef unsigned short u16;
typedef u16 u16x8 __attribute__((ext_vector_type(8)));
typedef short bf16x8 __attribute__((ext_vector_type(8)));
typedef float f32x4 __attribute__((ext_vector_type(4)));

#define NCONST 100000
#define MCONST 20000
#define ECONST 1600000
#define HCH2 32768  // histogram chunk (ints) = 128KB LDS
#define HBC 32      // blocks per chunk

#define PBLK 256        // partition blocks (1 chunk each)
#define PT 6250         // edges per partition chunk (E/PBLK)
#define SHB_IN 6        // coarse bucket shift, in-direction
#define NBK_IN 313      // ceil(M / 64)
#define SRCB_IN 17      // src bits (in_src < 2^17)
#define SHB_HAS 8       // coarse bucket shift, has-direction
#define NBK_HAS 391     // ceil(N / 256)
#define SRCB_HAS 15     // src bits (has_src < 2^15)

__device__ __forceinline__ u16 f2bf(float f) {  // RNE
  u32 u = __float_as_uint(f);
  u += 0x7FFFu + ((u >> 16) & 1u);
  return (u16)(u >> 16);
}
__device__ __forceinline__ float bf2f(u16 b) {
  return __uint_as_float(((u32)b) << 16);
}

// ---------------- histograms: one launch, LDS-private, no global atomics ----------------
// grid (HBC, 9): y=0 -> in_dst (M); y=1..4 -> has_dst chunks; y=5..8 -> in_src chunks.
__global__ __launch_bounds__(256) void k_hpart2(const int* __restrict__ in_dst,
                                                const int* __restrict__ has_dst,
                                                const int* __restrict__ in_src,
                                                int* __restrict__ partial) {
  __shared__ int hc[HCH2];
  int y = blockIdx.y;
  const int* __restrict__ arr = (y == 0) ? in_dst : (y <= 4 ? has_dst : in_src);
  int lo = (y == 0) ? 0 : (y <= 4 ? (y - 1) * HCH2 : (y - 5) * HCH2);
  for (int i = threadIdx.x; i < HCH2; i += 256) hc[i] = 0;
  __syncthreads();
  int stride = gridDim.x * 256;
  int n4 = ECONST >> 2;
  const int4* a4 = (const int4*)arr;
  for (int i = blockIdx.x * 256 + threadIdx.x; i < n4; i += stride) {
    int4 v = a4[i];
    u32 a = (u32)(v.x - lo), b = (u32)(v.y - lo), c = (u32)(v.z - lo), d = (u32)(v.w - lo);
    if (a < HCH2) atomicAdd(&hc[a], 1);
    if (b < HCH2) atomicAdd(&hc[b], 1);
    if (c < HCH2) atomicAdd(&hc[c], 1);
    if (d < HCH2) atomicAdd(&hc[d], 1);
  }
  __syncthreads();
  int* out = partial + ((size_t)y * HBC + blockIdx.x) * HCH2;
  for (int i = threadIdx.x; i < HCH2; i += 256) out[i] = hc[i];
}

// ---------------- scans: y=0 -> off_in (M), y=1 -> off_has (N), y=2 -> deg (raw sums)
__global__ void k_scan1d(const int* __restrict__ partial, int nM, int nN,
                         int* __restrict__ off_in, int* __restrict__ off_has,
                         int* __restrict__ deg, int* __restrict__ bsum) {
  __shared__ int sd[256];
  int y = blockIdx.y;
  int n = y ? nN : nM;
  int rowbase = (y == 0) ? 0 : (y == 1 ? 1 : 5);
  int t = threadIdx.x;
  int base = blockIdx.x * 1024 + t * 4;
  int v[4];
#pragma unroll
  for (int k = 0; k < 4; ++k) {
    int j = base + k;
    int s = 0;
    if (j < n) {
      int chunk = j >> 15;
      int jl = j & (HCH2 - 1);
      const int* p = partial + ((size_t)(rowbase + chunk) * HBC) * HCH2 + jl;
#pragma unroll
      for (int b = 0; b < HBC; ++b) s += p[(size_t)b * HCH2];
    }
    v[k] = s;
  }
  if (y == 2) {
#pragma unroll
    for (int k = 0; k < 4; ++k)
      if (base + k < n) deg[base + k] = v[k];
    return;
  }
  int* off = y ? off_has : off_in;
  int* bs = bsum + y * 128;
  v[1] += v[0]; v[2] += v[1]; v[3] += v[2];
  int tot = v[3];
  sd[t] = tot;
  __syncthreads();
  for (int o = 1; o < 256; o <<= 1) {
    int x = (t >= o) ? sd[t - o] : 0;
    __syncthreads();
    sd[t] += x;
    __syncthreads();
  }
  int excl = sd[t] - tot;
#pragma unroll
  for (int k = 0; k < 4; ++k)
    if (base + k < n) off[base + k + 1] = v[k] + excl;
  if (t == 255) bs[blockIdx.x] = sd[255];
}

__global__ void k_scan2d(int* __restrict__ bsum, int nbM, int nbN) {
  __shared__ int sd[256];
  int* bs = bsum + blockIdx.x * 128;
  int nb = blockIdx.x ? nbN : nbM;
  int t = threadIdx.x;
  int v = (t < nb) ? bs[t] : 0;
  sd[t] = v;
  __syncthreads();
  for (int o = 1; o < 256; o <<= 1) {
    int x = (t >= o) ? sd[t - o] : 0;
    __syncthreads();
    sd[t] += x;
    __syncthreads();
  }
  if (t < nb) bs[t] = sd[t] - v;  // exclusive
}

__global__ void k_scan3d(int* __restrict__ off_in, int* __restrict__ off_has,
                         const int* __restrict__ bsum, int nM, int nN) {
  int y = blockIdx.y;
  int* off = y ? off_has : off_in;
  const int* bs = bsum + y * 128;
  int n = y ? nN : nM;
  int i = blockIdx.x * blockDim.x + threadIdx.x;
  int st = gridDim.x * blockDim.x;
  if (blockIdx.x == 0 && threadIdx.x == 0) off[0] = 0;
  for (; i < n; i += st) off[i + 1] += bs[i >> 10];
}

// ---------------- scatter v3: atomic-free LDS-staged partition ----------------
__global__ __launch_bounds__(256) void k_coarse(const int* __restrict__ in_dst,
                                                const int* __restrict__ has_dst,
                                                int* __restrict__ bb_in,
                                                int* __restrict__ bb_has) {
  __shared__ int h1[NBK_IN];
  __shared__ int h2[NBK_HAS];
  for (int i = threadIdx.x; i < NBK_IN; i += 256) h1[i] = 0;
  for (int i = threadIdx.x; i < NBK_HAS; i += 256) h2[i] = 0;
  __syncthreads();
  int c0 = blockIdx.x * PT, c1 = min(c0 + PT, ECONST);
  for (int i = c0 + threadIdx.x; i < c1; i += 256) {
    atomicAdd(&h1[in_dst[i] >> SHB_IN], 1);
    atomicAdd(&h2[has_dst[i] >> SHB_HAS], 1);
  }
  __syncthreads();
  int* o1 = bb_in + (size_t)blockIdx.x * NBK_IN;
  for (int i = threadIdx.x; i < NBK_IN; i += 256) o1[i] = h1[i];
  int* o2 = bb_has + (size_t)blockIdx.x * NBK_HAS;
  for (int i = threadIdx.x; i < NBK_HAS; i += 256) o2[i] = h2[i];
}

template <int NBUK, int SHB>
__device__ __forceinline__ void colscan_body(int* __restrict__ bb,
                                             const int* __restrict__ off, int segs,
                                             int* sd) {
  int b = blockIdx.x;
  if (b >= NBUK) return;  // uniform per block
  int t = threadIdx.x;
  int v = bb[(size_t)t * NBUK + b];
  sd[t] = v;
  __syncthreads();
  for (int o = 1; o < 256; o <<= 1) {
    int x = (t >= o) ? sd[t - o] : 0;
    __syncthreads();
    sd[t] += x;
    __syncthreads();
  }
  bb[(size_t)t * NBUK + b] = sd[t] - v + off[min(b << SHB, segs)];
}

__global__ __launch_bounds__(256) void k_colscan2(int* __restrict__ bb_in,
                                                  const int* __restrict__ off_in,
                                                  int* __restrict__ bb_has,
                                                  const int* __restrict__ off_has) {
  __shared__ int sd[256];
  if (blockIdx.y == 0)
    colscan_body<NBK_IN, SHB_IN>(bb_in, off_in, MCONST, sd);
  else
    colscan_body<NBK_HAS, SHB_HAS>(bb_has, off_has, NCONST, sd);
}

template <int NBUK, int SHB, int SRCB>
__device__ __forceinline__ void stage_body(const int* __restrict__ dst,
                                           const int* __restrict__ srcv,
                                           const int* __restrict__ bb,
                                           int* __restrict__ ebuf, int* hist, int* loff,
                                           int* gbase, int* stg, int* sd) {
  int t = threadIdx.x;
  for (int i = t; i < NBUK; i += 256) hist[i] = 0;
  __syncthreads();
  int c0 = blockIdx.x * PT, c1 = min(c0 + PT, ECONST);
  for (int i = c0 + t; i < c1; i += 256) atomicAdd(&hist[dst[i] >> SHB], 1);
  __syncthreads();
  {
    int v0 = (2 * t < NBUK) ? hist[2 * t] : 0;
    int v1 = (2 * t + 1 < NBUK) ? hist[2 * t + 1] : 0;
    sd[t] = v0 + v1;
    __syncthreads();
    for (int o = 1; o < 256; o <<= 1) {
      int x = (t >= o) ? sd[t - o] : 0;
      __syncthreads();
      sd[t] += x;
      __syncthreads();
    }
    int excl = sd[t] - (v0 + v1);
    if (2 * t < NBUK) loff[2 * t] = excl;
    if (2 * t + 1 < NBUK) loff[2 * t + 1] = excl + v0;
  }
  __syncthreads();
  for (int i = t; i < NBUK; i += 256) {
    gbase[i] = bb[(size_t)blockIdx.x * NBUK + i];
    hist[i] = loff[i];  // cursor
  }
  __syncthreads();
  for (int i = c0 + t; i < c1; i += 256) {
    int d = dst[i], s = srcv[i];
    int b = d >> SHB;
    int r = atomicAdd(&hist[b], 1);
    stg[r] = (b << 23) | ((d & ((1 << SHB) - 1)) << SRCB) | s;
  }
  __syncthreads();
  int tot = c1 - c0;
  for (int i = t; i < tot; i += 256) {
    int v = stg[i];
    int b = ((u32)v) >> 23;
    ebuf[gbase[b] + (i - loff[b])] = v & ((1 << 23) - 1);
  }
}

__global__ __launch_bounds__(256) void k_stage2(
    const int* __restrict__ in_dst, const int* __restrict__ in_src,
    const int* __restrict__ bb_in, int* __restrict__ ebuf_in,
    const int* __restrict__ has_dst, const int* __restrict__ has_src,
    const int* __restrict__ bb_has, int* __restrict__ ebuf_has) {
  __shared__ int hist[NBK_HAS];
  __shared__ int loff[NBK_HAS];
  __shared__ int gbase[NBK_HAS];
  __shared__ int stg[PT];
  __shared__ int sd[256];
  if (blockIdx.y == 0)
    stage_body<NBK_IN, SHB_IN, SRCB_IN>(in_dst, in_src, bb_in, ebuf_in, hist, loff, gbase,
                                        stg, sd);
  else
    stage_body<NBK_HAS, SHB_HAS, SRCB_HAS>(has_dst, has_src, bb_has, ebuf_has, hist, loff,
                                           gbase, stg, sd);
}

template <int SHB, int SRCB>
__device__ __forceinline__ void place_body(const int* __restrict__ off, int segs,
                                           const int* __restrict__ ebuf,
                                           int* __restrict__ csrc, int* cur) {
  const int NSEG = 1 << SHB;
  int seg0 = blockIdx.x << SHB;
  if (seg0 >= segs) return;  // uniform per block
  int segN = min(seg0 + NSEG, segs);
  for (int i = threadIdx.x; i < segN - seg0; i += 256) cur[i] = off[seg0 + i];
  __syncthreads();
  int start = off[seg0], end = off[segN];
  for (int i = start + threadIdx.x; i < end; i += 256) {
    int v = ebuf[i];
    int dloc = ((u32)v) >> SRCB;
    int pos = atomicAdd(&cur[dloc], 1);
    csrc[pos] = v & ((1 << SRCB) - 1);
  }
}

__global__ __launch_bounds__(256) void k_place2(
    const int* __restrict__ off_in, const int* __restrict__ ebuf_in,
    int* __restrict__ csrc_in, const int* __restrict__ off_has,
    const int* __restrict__ ebuf_has, int* __restrict__ csrc_has) {
  __shared__ int cur[256];
  if (blockIdx.y == 0)
    place_body<SHB_IN, SRCB_IN>(off_in, MCONST, ebuf_in, csrc_in, cur);
  else
    place_body<SHB_HAS, SRCB_HAS>(off_has, NCONST, ebuf_has, csrc_has, cur);
}

// ---------------- online softmax merge helper ----------------
__device__ __forceinline__ void merge_write(float m, float s, float2* __restrict__ pairs) {
  for (int o = 1; o < 64; o <<= 1) {
    float om = __shfl_xor(m, o, 64), os = __shfl_xor(s, o, 64);
    float nm = fmaxf(m, om);
    s = s * __expf(m - nm) + os * __expf(om - nm);
    m = nm;
  }
  __shared__ float sm[4], ss[4];
  int t = threadIdx.x;
  if ((t & 63) == 0) { sm[t >> 6] = m; ss[t >> 6] = s; }
  __syncthreads();
  if (t == 0) {
    for (int k = 1; k < 4; ++k) {
      float nm = fmaxf(m, sm[k]);
      s = s * __expf(m - nm) + ss[k] * __expf(sm[k] - nm);
      m = nm;
    }
    pairs[blockIdx.x] = make_float2(m, s);
  }
}

// ---------------- FC: h = x@W + b (bf16 out), na = h@an, fused softmax1 pair ------------
// IT = float (layer 1) or u16 (layer 2, bf16 bits). SCALE: multiply x by scal_c[4] (=1/S2).
template <typename IT, bool SCALE>
__global__ __launch_bounds__(256, 3) void k_fc(
    const IT* __restrict__ x, const float* __restrict__ W,
    const float* __restrict__ bias, const float* __restrict__ an,
    const int* __restrict__ deg, const float* __restrict__ scal_c,
    u16* __restrict__ h, float* __restrict__ na, float2* __restrict__ pairs, int nrows) {
  __shared__ __align__(16) u16 sWT[128 * 136];
  __shared__ float sNa[128];
  int tid = threadIdx.x;
  int lane = tid & 63, w = tid >> 6;
  int cl = lane & 15, qg = lane >> 4;
  float C = SCALE ? scal_c[4] : 1.0f;

  for (int i = tid * 4; i < 16384; i += 1024) {
    float4 v = *(const float4*)(W + i);
    int k = i >> 7, j = i & 127;
    sWT[(j + 0) * 136 + k] = f2bf(v.x);
    sWT[(j + 1) * 136 + k] = f2bf(v.y);
    sWT[(j + 2) * 136 + k] = f2bf(v.z);
    sWT[(j + 3) * 136 + k] = f2bf(v.w);
  }

  float anv[8], bv[8];
#pragma unroll
  for (int t = 0; t < 8; ++t) {
    anv[t] = an[t * 16 + cl];
    bv[t] = bias[t * 16 + cl];
  }

  int rbase = blockIdx.x * 128 + w * 32;
  bf16x8 afr[2][4];
#pragma unroll
  for (int g = 0; g < 2; ++g) {
    int r = rbase + g * 16 + cl;
    int rc = min(r, nrows - 1);
    const IT* xp = x + (size_t)rc * 128 + qg * 8;
#pragma unroll
    for (int s = 0; s < 4; ++s) {
      if constexpr (sizeof(IT) == 4) {
        float4 u0 = *(const float4*)(xp + s * 32);
        float4 u1 = *(const float4*)(xp + s * 32 + 4);
        bf16x8 a;
        a[0] = (short)f2bf(u0.x); a[1] = (short)f2bf(u0.y);
        a[2] = (short)f2bf(u0.z); a[3] = (short)f2bf(u0.w);
        a[4] = (short)f2bf(u1.x); a[5] = (short)f2bf(u1.y);
        a[6] = (short)f2bf(u1.z); a[7] = (short)f2bf(u1.w);
        afr[g][s] = a;
      } else {
        bf16x8 a = *(const bf16x8*)(xp + s * 32);
        if constexpr (SCALE) {
#pragma unroll
          for (int j = 0; j < 8; ++j) a[j] = (short)f2bf(bf2f((u16)a[j]) * C);
        }
        afr[g][s] = a;
      }
    }
  }
  __syncthreads();

  f32x4 acc[2][8];
#pragma unroll
  for (int g = 0; g < 2; ++g)
#pragma unroll
    for (int t = 0; t < 8; ++t) {
      acc[g][t][0] = 0.f; acc[g][t][1] = 0.f; acc[g][t][2] = 0.f; acc[g][t][3] = 0.f;
    }

#pragma unroll
  for (int t = 0; t < 8; ++t) {
    bf16x8 bfrg[4];
    const u16* bp = sWT + (t * 16 + cl) * 136 + qg * 8;
#pragma unroll
    for (int s = 0; s < 4; ++s) bfrg[s] = *(const bf16x8*)(bp + s * 32);
#pragma unroll
    for (int s = 0; s < 4; ++s) {
#pragma unroll
      for (int g = 0; g < 2; ++g)
        acc[g][t] = __builtin_amdgcn_mfma_f32_16x16x32_bf16(afr[g][s], bfrg[s], acc[g][t],
                                                            0, 0, 0);
    }
  }

  float pa[2][4];
#pragma unroll
  for (int g = 0; g < 2; ++g)
#pragma unroll
    for (int reg = 0; reg < 4; ++reg) pa[g][reg] = 0.f;
#pragma unroll
  for (int g = 0; g < 2; ++g)
#pragma unroll
    for (int t = 0; t < 8; ++t)
#pragma unroll
      for (int reg = 0; reg < 4; ++reg)
        pa[g][reg] = fmaf(acc[g][t][reg] + bv[t], anv[t], pa[g][reg]);
#pragma unroll
  for (int g = 0; g < 2; ++g)
#pragma unroll
    for (int reg = 0; reg < 4; ++reg) {
      float v = pa[g][reg];
      v += __shfl_xor(v, 1, 64);
      v += __shfl_xor(v, 2, 64);
      v += __shfl_xor(v, 4, 64);
      v += __shfl_xor(v, 8, 64);
      pa[g][reg] = v;
    }
  if (cl == 0) {
#pragma unroll
    for (int g = 0; g < 2; ++g)
#pragma unroll
      for (int reg = 0; reg < 4; ++reg) {
        int r = rbase + g * 16 + qg * 4 + reg;
        int lidx = w * 32 + g * 16 + qg * 4 + reg;
        if (r < nrows) {
          na[r] = pa[g][reg];
          sNa[lidx] = pa[g][reg];
        }
      }
  }

  __syncthreads();
  u16* st = sWT + w * 32 * 136;
#pragma unroll
  for (int g = 0; g < 2; ++g)
#pragma unroll
    for (int t = 0; t < 8; ++t)
#pragma unroll
      for (int reg = 0; reg < 4; ++reg)
        st[(g * 16 + qg * 4 + reg) * 136 + t * 16 + cl] = f2bf(acc[g][t][reg] + bv[t]);
#pragma unroll
  for (int it = 0; it < 8; ++it) {
    int idx = it * 64 + lane;
    int row = idx >> 4, c = idx & 15;
    u16x8 v = *(const u16x8*)(st + row * 136 + c * 8);
    int r = rbase + row;
    if (r < nrows) *(u16x8*)(h + (size_t)r * 128 + c * 8) = v;
  }

  // fused softmax1 partial: per-node (m = na, s = deg); block online-merge.
  float m1 = -1e30f, s1 = 0.f;
  if (tid < 128) {
    int r = blockIdx.x * 128 + tid;
    if (r < nrows) {
      int d = deg[r];
      if (d > 0) { m1 = sNa[tid]; s1 = (float)d; }
    }
  }
  merge_write(m1, s1, pairs);
}

__global__ void k_smfin(const float2* __restrict__ pairs, int nb, float* __restrict__ out) {
  int t = threadIdx.x;
  float m = -1e30f, s = 0.f;
  for (int i = t; i < nb; i += 256) {
    float2 pr = pairs[i];
    float nm = fmaxf(m, pr.x);
    s = s * __expf(m - nm) + pr.y * __expf(pr.x - nm);
    m = nm;
  }
  for (int o = 1; o < 64; o <<= 1) {
    float om = __shfl_xor(m, o, 64), os = __shfl_xor(s, o, 64);
    float nm = fmaxf(m, om);
    s = s * __expf(m - nm) + os * __expf(om - nm);
    m = nm;
  }
  __shared__ float sm[4], ss[4];
  if ((t & 63) == 0) { sm[t >> 6] = m; ss[t >> 6] = s; }
  __syncthreads();
  if (t == 0) {
    for (int k = 1; k < 4; ++k) {
      float nm = fmaxf(m, sm[k]);
      s = s * __expf(m - nm) + ss[k] * __expf(sm[k] - nm);
      m = nm;
    }
    out[0] = m;
    out[1] = s;
  }
}

// wn[i] = exp(na[i]-mx1)*iz1 (segAs gathers this; avoids 8x-duplicated exp)
__global__ __launch_bounds__(256) void k_wnode(const float* __restrict__ na,
                                               const float* __restrict__ scal,
                                               float* __restrict__ wn, int n) {
  int i = blockIdx.x * 256 + threadIdx.x;
  if (i < n) wn[i] = __expf(na[i] - scal[0]) * (1.0f / scal[1]);
}

// ---------------- segA, XCD column-sliced ----------------
// grid = ceil(M/4)*8 blocks; bid = g*8 + slice. slice -> XCD via round-robin id mapping.
// Wave handles one (segment, slice): 32 edge-slots x 2 col-chunks; 32B of h per edge.
__global__ __launch_bounds__(256) void k_segAs(
    const u16* __restrict__ h, const float* __restrict__ wn,
    const int* __restrict__ csrc, const int* __restrict__ off,
    u16* __restrict__ he, int m_count) {
  int bid = blockIdx.x;
  int slice = bid & 7;
  int wid = (bid >> 3) * 4 + (threadIdx.x >> 6);
  if (wid >= m_count) return;
  int lane = threadIdx.x & 63;
  int eslot = lane >> 1, ch = lane & 1;
  int col = slice * 16 + ch * 8;
  int s = off[wid], t = off[wid + 1];
  float ax[8];
#pragma unroll
  for (int j = 0; j < 8; ++j) ax[j] = 0.f;
  for (int i = s + eslot; i < t; i += 32) {
    int sr = csrc[i];
    float ww = wn[sr];
    u16x8 v = *(const u16x8*)(h + (size_t)sr * 128 + col);
#pragma unroll
    for (int j = 0; j < 8; ++j) ax[j] = fmaf(ww, bf2f(v[j]), ax[j]);
  }
#pragma unroll
  for (int j = 0; j < 8; ++j) {
    ax[j] += __shfl_xor(ax[j], 2, 64);
    ax[j] += __shfl_xor(ax[j], 4, 64);
    ax[j] += __shfl_xor(ax[j], 8, 64);
    ax[j] += __shfl_xor(ax[j], 16, 64);
    ax[j] += __shfl_xor(ax[j], 32, 64);
  }
  if (eslot == 0) {
    u16x8 o;
#pragma unroll
    for (int j = 0; j < 8; ++j) o[j] = f2bf(ax[j]);
    *(u16x8*)(he + (size_t)wid * 128 + col) = o;
  }
}

// ea = he @ ae (he is 5MB, streamed; 16 rows per 256-block)
__global__ __launch_bounds__(256) void k_ea(const u16* __restrict__ he,
                                            const float* __restrict__ ae,
                                            float* __restrict__ ea, int m) {
  int row = blockIdx.x * 16 + (threadIdx.x >> 4);
  int cl = threadIdx.x & 15;
  if (row >= m) return;
  u16x8 v = *(const u16x8*)(he + (size_t)row * 128 + cl * 8);
  float4 a0 = *(const float4*)(ae + cl * 8);
  float4 a1 = *(const float4*)(ae + cl * 8 + 4);
  float pa = bf2f(v[0]) * a0.x + bf2f(v[1]) * a0.y + bf2f(v[2]) * a0.z +
             bf2f(v[3]) * a0.w + bf2f(v[4]) * a1.x + bf2f(v[5]) * a1.y +
             bf2f(v[6]) * a1.z + bf2f(v[7]) * a1.w;
  pa += __shfl_xor(pa, 1, 64);
  pa += __shfl_xor(pa, 2, 64);
  pa += __shfl_xor(pa, 4, 64);
  pa += __shfl_xor(pa, 8, 64);
  if (cl == 0) ea[row] = pa;
}

// softmax2, CSR form (layer 2 only): per node i, online over its has-segment.
__global__ void k_sm2c(const float* __restrict__ na, const float* __restrict__ ea,
                       const int* __restrict__ csrc, const int* __restrict__ off, int n,
                       float2* __restrict__ pairs) {
  float m = -1e30f, s = 0.f;
  int gid = blockIdx.x * 256 + threadIdx.x;
  int stride = gridDim.x * 256;
  for (int i = gid; i < n; i += stride) {
    float nav = na[i];
    int a = off[i], b = off[i + 1];
    for (int j = a; j < b; ++j) {
      float xv = nav + ea[csrc[j]];
      if (xv > m) { s *= __expf(m - xv); m = xv; }
      s += __expf(xv - m);
    }
  }
  merge_write(m, s, pairs);
}

// sum of segB<1>'s S2 partials -> scal[4] = 1/S2
__global__ void k_s2fin(const float2* __restrict__ pairs, int nb, float* __restrict__ out) {
  int t = threadIdx.x;
  float s = 0.f;
  for (int i = t; i < nb; i += 256) s += pairs[i].x;
  for (int o = 1; o < 64; o <<= 1) s += __shfl_xor(s, o, 64);
  __shared__ float sm[4];
  if ((t & 63) == 0) sm[t >> 6] = s;
  __syncthreads();
  if (t == 0) out[4] = 1.0f / (sm[0] + sm[1] + sm[2] + sm[3]);
}

// ---------------- segB (one wave/segment, 16B/lane, 4 edges/iter) ----------------
// L1=1: UNSCALED u = exp(na+ea)*he (relu, bf16 out) + per-block S2 partial -> pairs.
// L1=0: scaled by scal[2,3], fp32 out.
template <int L1>
__global__ __launch_bounds__(256) void k_segB(
    const u16* __restrict__ he, const float* __restrict__ ea,
    const float* __restrict__ na, const float* __restrict__ scal,
    const int* __restrict__ csrc, const int* __restrict__ off,
    void* __restrict__ yout, float2* __restrict__ pairs, int n_count) {
  __shared__ float swv[4];
  int wv = threadIdx.x >> 6;
  int wid = (blockIdx.x << 2) + wv;
  int lane = threadIdx.x & 63;
  int sub = lane >> 4, cl = lane & 15;
  float sx = 0.f;
  if (wid < n_count) {
    float mx2 = L1 ? 0.f : scal[2];
    float iz2 = L1 ? 1.f : (1.0f / scal[3]);
    float nav = na[wid];
    int s = off[wid], t = off[wid + 1];
    float ax[8];
#pragma unroll
    for (int j = 0; j < 8; ++j) ax[j] = 0.f;
    for (int i = s + sub; i < t; i += 4) {
      int sr = csrc[i];
      float c = __expf(ea[sr] + nav - mx2) * iz2;
      if (L1 && cl == 0) sx += c;
      u16x8 v = *(const u16x8*)(he + (size_t)sr * 128 + cl * 8);
#pragma unroll
      for (int j = 0; j < 8; ++j) ax[j] = fmaf(c, bf2f(v[j]), ax[j]);
    }
#pragma unroll
    for (int j = 0; j < 8; ++j) {
      ax[j] += __shfl_xor(ax[j], 16, 64);
      ax[j] += __shfl_xor(ax[j], 32, 64);
      if (L1) ax[j] = fmaxf(ax[j], 0.f);
    }
    if (sub == 0) {
      if (L1) {
        u16x8 o;
#pragma unroll
        for (int j = 0; j < 8; ++j) o[j] = f2bf(ax[j]);
        *(u16x8*)((u16*)yout + (size_t)wid * 128 + cl * 8) = o;
      } else {
        float4 A = make_float4(ax[0], ax[1], ax[2], ax[3]);
        float4 B = make_float4(ax[4], ax[5], ax[6], ax[7]);
        float* y = (float*)yout;
        *(float4*)(y + (size_t)wid * 128 + cl * 8) = A;
        *(float4*)(y + (size_t)wid * 128 + cl * 8 + 4) = B;
      }
    }
  }
  if (L1) {
    for (int o = 1; o < 64; o <<= 1) sx += __shfl_xor(sx, o, 64);
    if (lane == 0) swv[wv] = sx;
    __syncthreads();
    if (threadIdx.x == 0)
      pairs[blockIdx.x] = make_float2(swv[0] + swv[1] + swv[2] + swv[3], 0.f);
  }
}

// ---------------- host ----------------
extern "C" void kernel_launch(void* const* d_in, const int* in_sizes, int n_in,
                              void* d_out, int out_size, void* d_ws, size_t ws_size,
                              hipStream_t stream) {
  const int N = NCONST, M = MCONST, E = ECONST;
  const float* x = (const float*)d_in[0];
  const int* in_src = (const int*)d_in[1];
  const int* in_dst = (const int*)d_in[2];
  const int* has_src = (const int*)d_in[3];
  const int* has_dst = (const int*)d_in[4];
  const float* W1 = (const float*)d_in[5];
  const float* b1 = (const float*)d_in[6];
  const float* an1 = (const float*)d_in[7];
  const float* ae1 = (const float*)d_in[8];
  const float* W2 = (const float*)d_in[9];
  const float* b2 = (const float*)d_in[10];
  const float* an2 = (const float*)d_in[11];
  const float* ae2 = (const float*)d_in[12];

  const size_t PARTIAL_BYTES = (size_t)9 * HBC * HCH2 * 4;  // 37.7 MB

  char* p = (char*)d_ws;
  auto alloc = [&](size_t bytes) {
    char* q = p;
    p += (bytes + 255) & ~(size_t)255;
    return q;
  };
  u16* h = (u16*)alloc((size_t)N * 128 * 2);
  u16* he = (u16*)alloc((size_t)M * 128 * 2);
  float* na = (float*)alloc((size_t)N * 4);
  float* ea = (float*)alloc((size_t)M * 4);
  float* wn = (float*)alloc((size_t)N * 4);
  int* deg = (int*)alloc((size_t)N * 4);
  int* off_in = (int*)alloc((size_t)(M + 1) * 4);
  int* off_has = (int*)alloc((size_t)(N + 1) * 4);
  int* csrc_in = (int*)alloc((size_t)E * 4);
  int* csrc_has = (int*)alloc((size_t)E * 4);
  int* partial = (int*)alloc(PARTIAL_BYTES);  // unions with ebufs (disjoint lifetime)
  int* ebuf_in = partial;
  int* ebuf_has = partial + ECONST;
  int* bb_in = (int*)alloc((size_t)PBLK * NBK_IN * 4);
  int* bb_has = (int*)alloc((size_t)PBLK * NBK_HAS * 4);
  int* bsum = (int*)alloc(256 * 4);
  float2* pairs = (float2*)alloc((size_t)25600 * 8);
  float* scal = (float*)alloc(64);
  if ((size_t)(p - (char*)d_ws) > ws_size) return;  // insufficient workspace

  u16* y1b = (u16*)d_out;  // layer-1 bf16 (UNSCALED) output staged in d_out bytes;
                           // fc2 scales by scal[4]=1/S2; final fp32 overwrites in segB<0>.

  // histograms (one launch) + merged scans (+ deg reduction as y=2)
  k_hpart2<<<dim3(HBC, 9), 256, 0, stream>>>(in_dst, has_dst, in_src, partial);
  int nbM = (M + 1023) / 1024, nbN = (N + 1023) / 1024;
  k_scan1d<<<dim3(nbN, 3), 256, 0, stream>>>(partial, M, N, off_in, off_has, deg, bsum);
  k_scan2d<<<2, 256, 0, stream>>>(bsum, nbM, nbN);
  k_scan3d<<<dim3(512, 2), 256, 0, stream>>>(off_in, off_has, bsum, M, N);

  // scatter v3 (atomic-free partition), directions merged via blockIdx.y
  k_coarse<<<PBLK, 256, 0, stream>>>(in_dst, has_dst, bb_in, bb_has);
  k_colscan2<<<dim3(NBK_HAS, 2), 256, 0, stream>>>(bb_in, off_in, bb_has, off_has);
  k_stage2<<<dim3(PBLK, 2), 256, 0, stream>>>(in_dst, in_src, bb_in, ebuf_in, has_dst,
                                              has_src, bb_has, ebuf_has);
  k_place2<<<dim3(NBK_HAS, 2), 256, 0, stream>>>(off_in, ebuf_in, csrc_in, off_has,
                                                 ebuf_has, csrc_has);

  const int FCB = (N + 127) / 128;        // 782 fc blocks
  const int SAB = ((M + 3) / 4) * 8;      // 40000 sliced-segA blocks
  const int SBB = (N + 3) / 4;            // 25000 segB blocks

  // ---- layer 1 ----
  k_fc<float, false><<<FCB, 256, 0, stream>>>(x, W1, b1, an1, deg, scal, h, na, pairs, N);
  k_smfin<<<1, 256, 0, stream>>>(pairs, FCB, scal);  // scal[0,1] = mx1, S1
  k_wnode<<<(N + 255) / 256, 256, 0, stream>>>(na, scal, wn, N);
  k_segAs<<<SAB, 256, 0, stream>>>(h, wn, csrc_in, off_in, he, M);
  k_ea<<<(M + 15) / 16, 256, 0, stream>>>(he, ae1, ea, M);
  k_segB<1><<<SBB, 256, 0, stream>>>(he, ea, na, scal, csrc_has, off_has, (void*)y1b,
                                     pairs, N);
  k_s2fin<<<1, 256, 0, stream>>>(pairs, SBB, scal);  // scal[4] = 1/S2

  // ---- layer 2 ----
  k_fc<u16, true><<<FCB, 256, 0, stream>>>(y1b, W2, b2, an2, deg, scal, h, na, pairs, N);
  k_smfin<<<1, 256, 0, stream>>>(pairs, FCB, scal);  // scal[0,1] for layer 2
  k_wnode<<<(N + 255) / 256, 256, 0, stream>>>(na, scal, wn, N);
  k_segAs<<<SAB, 256, 0, stream>>>(h, wn, csrc_in, off_in, he, M);
  k_ea<<<(M + 15) / 16, 256, 0, stream>>>(he, ae2, ea, M);
  k_sm2c<<<128, 256, 0, stream>>>(na, ea, csrc_has, off_has, N, pairs);
  k_smfin<<<1, 256, 0, stream>>>(pairs, 128, scal + 2);  // scal[2,3]
  k_segB<0><<<SBB, 256, 0, stream>>>(he, ea, na, scal, csrc_has, off_has, d_out, pairs, N);
}

// Round 13
// 503.366 us; speedup vs baseline: 1.4618x; 1.4618x over previous
//
#include <hip/hip_runtime.h>
#include <hip/hip_bf16.h>
#include <math.h>
#include <type_traits>

// HGAT: 2-layer hypergraph attention. N nodes, M hyperedges, E incidence edges, D=128.
// R13: revert R12's XCD column-sliced segA (FAILED: 613MB fetch — 32B/64B line waste +
// 6.4MB/XCD effective working set > 4MB L2; 177us vs 64us). Back to R10's fused segA
// (inline exp + inline ea, one wave/segment, 16B/lane). KEEP R11's orthogonal wins:
// layer-1 sm2 eliminated via deferred 1/S2 scaling (segB<1> unscaled + partials, fc2
// scales input); layer-2 sm2 via CSR (k_sm2c, 6.4MB vs 12.8MB).
// Scatter v3 (R8), MFMA fc + fused softmax1 (R10), bf16 rows (R3). 19 dispatches.

typedef unsigned int u32;
typedef unsigned short u16;
typedef u16 u16x8 __attribute__((ext_vector_type(8)));
typedef short bf16x8 __attribute__((ext_vector_type(8)));
typedef float f32x4 __attribute__((ext_vector_type(4)));

#define NCONST 100000
#define MCONST 20000
#define ECONST 1600000
#define HCH2 32768  // histogram chunk (ints) = 128KB LDS
#define HBC 32      // blocks per chunk

#define PBLK 256        // partition blocks (1 chunk each)
#define PT 6250         // edges per partition chunk (E/PBLK)
#define SHB_IN 6        // coarse bucket shift, in-direction
#define NBK_IN 313      // ceil(M / 64)
#define SRCB_IN 17      // src bits (in_src < 2^17)
#define SHB_HAS 8       // coarse bucket shift, has-direction
#define NBK_HAS 391     // ceil(N / 256)
#define SRCB_HAS 15     // src bits (has_src < 2^15)

__device__ __forceinline__ u16 f2bf(float f) {  // RNE
  u32 u = __float_as_uint(f);
  u += 0x7FFFu + ((u >> 16) & 1u);
  return (u16)(u >> 16);
}
__device__ __forceinline__ float bf2f(u16 b) {
  return __uint_as_float(((u32)b) << 16);
}

// ---------------- histograms: one launch, LDS-private, no global atomics ----------------
// grid (HBC, 9): y=0 -> in_dst (M); y=1..4 -> has_dst chunks; y=5..8 -> in_src chunks.
__global__ __launch_bounds__(256) void k_hpart2(const int* __restrict__ in_dst,
                                                const int* __restrict__ has_dst,
                                                const int* __restrict__ in_src,
                                                int* __restrict__ partial) {
  __shared__ int hc[HCH2];
  int y = blockIdx.y;
  const int* __restrict__ arr = (y == 0) ? in_dst : (y <= 4 ? has_dst : in_src);
  int lo = (y == 0) ? 0 : (y <= 4 ? (y - 1) * HCH2 : (y - 5) * HCH2);
  for (int i = threadIdx.x; i < HCH2; i += 256) hc[i] = 0;
  __syncthreads();
  int stride = gridDim.x * 256;
  int n4 = ECONST >> 2;
  const int4* a4 = (const int4*)arr;
  for (int i = blockIdx.x * 256 + threadIdx.x; i < n4; i += stride) {
    int4 v = a4[i];
    u32 a = (u32)(v.x - lo), b = (u32)(v.y - lo), c = (u32)(v.z - lo), d = (u32)(v.w - lo);
    if (a < HCH2) atomicAdd(&hc[a], 1);
    if (b < HCH2) atomicAdd(&hc[b], 1);
    if (c < HCH2) atomicAdd(&hc[c], 1);
    if (d < HCH2) atomicAdd(&hc[d], 1);
  }
  __syncthreads();
  int* out = partial + ((size_t)y * HBC + blockIdx.x) * HCH2;
  for (int i = threadIdx.x; i < HCH2; i += 256) out[i] = hc[i];
}

// ---------------- scans: y=0 -> off_in (M), y=1 -> off_has (N), y=2 -> deg (raw sums)
__global__ void k_scan1d(const int* __restrict__ partial, int nM, int nN,
                         int* __restrict__ off_in, int* __restrict__ off_has,
                         int* __restrict__ deg, int* __restrict__ bsum) {
  __shared__ int sd[256];
  int y = blockIdx.y;
  int n = y ? nN : nM;
  int rowbase = (y == 0) ? 0 : (y == 1 ? 1 : 5);
  int t = threadIdx.x;
  int base = blockIdx.x * 1024 + t * 4;
  int v[4];
#pragma unroll
  for (int k = 0; k < 4; ++k) {
    int j = base + k;
    int s = 0;
    if (j < n) {
      int chunk = j >> 15;
      int jl = j & (HCH2 - 1);
      const int* p = partial + ((size_t)(rowbase + chunk) * HBC) * HCH2 + jl;
#pragma unroll
      for (int b = 0; b < HBC; ++b) s += p[(size_t)b * HCH2];
    }
    v[k] = s;
  }
  if (y == 2) {
#pragma unroll
    for (int k = 0; k < 4; ++k)
      if (base + k < n) deg[base + k] = v[k];
    return;
  }
  int* off = y ? off_has : off_in;
  int* bs = bsum + y * 128;
  v[1] += v[0]; v[2] += v[1]; v[3] += v[2];
  int tot = v[3];
  sd[t] = tot;
  __syncthreads();
  for (int o = 1; o < 256; o <<= 1) {
    int x = (t >= o) ? sd[t - o] : 0;
    __syncthreads();
    sd[t] += x;
    __syncthreads();
  }
  int excl = sd[t] - tot;
#pragma unroll
  for (int k = 0; k < 4; ++k)
    if (base + k < n) off[base + k + 1] = v[k] + excl;
  if (t == 255) bs[blockIdx.x] = sd[255];
}

__global__ void k_scan2d(int* __restrict__ bsum, int nbM, int nbN) {
  __shared__ int sd[256];
  int* bs = bsum + blockIdx.x * 128;
  int nb = blockIdx.x ? nbN : nbM;
  int t = threadIdx.x;
  int v = (t < nb) ? bs[t] : 0;
  sd[t] = v;
  __syncthreads();
  for (int o = 1; o < 256; o <<= 1) {
    int x = (t >= o) ? sd[t - o] : 0;
    __syncthreads();
    sd[t] += x;
    __syncthreads();
  }
  if (t < nb) bs[t] = sd[t] - v;  // exclusive
}

__global__ void k_scan3d(int* __restrict__ off_in, int* __restrict__ off_has,
                         const int* __restrict__ bsum, int nM, int nN) {
  int y = blockIdx.y;
  int* off = y ? off_has : off_in;
  const int* bs = bsum + y * 128;
  int n = y ? nN : nM;
  int i = blockIdx.x * blockDim.x + threadIdx.x;
  int st = gridDim.x * blockDim.x;
  if (blockIdx.x == 0 && threadIdx.x == 0) off[0] = 0;
  for (; i < n; i += st) off[i + 1] += bs[i >> 10];
}

// ---------------- scatter v3: atomic-free LDS-staged partition ----------------
__global__ __launch_bounds__(256) void k_coarse(const int* __restrict__ in_dst,
                                                const int* __restrict__ has_dst,
                                                int* __restrict__ bb_in,
                                                int* __restrict__ bb_has) {
  __shared__ int h1[NBK_IN];
  __shared__ int h2[NBK_HAS];
  for (int i = threadIdx.x; i < NBK_IN; i += 256) h1[i] = 0;
  for (int i = threadIdx.x; i < NBK_HAS; i += 256) h2[i] = 0;
  __syncthreads();
  int c0 = blockIdx.x * PT, c1 = min(c0 + PT, ECONST);
  for (int i = c0 + threadIdx.x; i < c1; i += 256) {
    atomicAdd(&h1[in_dst[i] >> SHB_IN], 1);
    atomicAdd(&h2[has_dst[i] >> SHB_HAS], 1);
  }
  __syncthreads();
  int* o1 = bb_in + (size_t)blockIdx.x * NBK_IN;
  for (int i = threadIdx.x; i < NBK_IN; i += 256) o1[i] = h1[i];
  int* o2 = bb_has + (size_t)blockIdx.x * NBK_HAS;
  for (int i = threadIdx.x; i < NBK_HAS; i += 256) o2[i] = h2[i];
}

template <int NBUK, int SHB>
__device__ __forceinline__ void colscan_body(int* __restrict__ bb,
                                             const int* __restrict__ off, int segs,
                                             int* sd) {
  int b = blockIdx.x;
  if (b >= NBUK) return;  // uniform per block
  int t = threadIdx.x;
  int v = bb[(size_t)t * NBUK + b];
  sd[t] = v;
  __syncthreads();
  for (int o = 1; o < 256; o <<= 1) {
    int x = (t >= o) ? sd[t - o] : 0;
    __syncthreads();
    sd[t] += x;
    __syncthreads();
  }
  bb[(size_t)t * NBUK + b] = sd[t] - v + off[min(b << SHB, segs)];
}

__global__ __launch_bounds__(256) void k_colscan2(int* __restrict__ bb_in,
                                                  const int* __restrict__ off_in,
                                                  int* __restrict__ bb_has,
                                                  const int* __restrict__ off_has) {
  __shared__ int sd[256];
  if (blockIdx.y == 0)
    colscan_body<NBK_IN, SHB_IN>(bb_in, off_in, MCONST, sd);
  else
    colscan_body<NBK_HAS, SHB_HAS>(bb_has, off_has, NCONST, sd);
}

template <int NBUK, int SHB, int SRCB>
__device__ __forceinline__ void stage_body(const int* __restrict__ dst,
                                           const int* __restrict__ srcv,
                                           const int* __restrict__ bb,
                                           int* __restrict__ ebuf, int* hist, int* loff,
                                           int* gbase, int* stg, int* sd) {
  int t = threadIdx.x;
  for (int i = t; i < NBUK; i += 256) hist[i] = 0;
  __syncthreads();
  int c0 = blockIdx.x * PT, c1 = min(c0 + PT, ECONST);
  for (int i = c0 + t; i < c1; i += 256) atomicAdd(&hist[dst[i] >> SHB], 1);
  __syncthreads();
  {
    int v0 = (2 * t < NBUK) ? hist[2 * t] : 0;
    int v1 = (2 * t + 1 < NBUK) ? hist[2 * t + 1] : 0;
    sd[t] = v0 + v1;
    __syncthreads();
    for (int o = 1; o < 256; o <<= 1) {
      int x = (t >= o) ? sd[t - o] : 0;
      __syncthreads();
      sd[t] += x;
      __syncthreads();
    }
    int excl = sd[t] - (v0 + v1);
    if (2 * t < NBUK) loff[2 * t] = excl;
    if (2 * t + 1 < NBUK) loff[2 * t + 1] = excl + v0;
  }
  __syncthreads();
  for (int i = t; i < NBUK; i += 256) {
    gbase[i] = bb[(size_t)blockIdx.x * NBUK + i];
    hist[i] = loff[i];  // cursor
  }
  __syncthreads();
  for (int i = c0 + t; i < c1; i += 256) {
    int d = dst[i], s = srcv[i];
    int b = d >> SHB;
    int r = atomicAdd(&hist[b], 1);
    stg[r] = (b << 23) | ((d & ((1 << SHB) - 1)) << SRCB) | s;
  }
  __syncthreads();
  int tot = c1 - c0;
  for (int i = t; i < tot; i += 256) {
    int v = stg[i];
    int b = ((u32)v) >> 23;
    ebuf[gbase[b] + (i - loff[b])] = v & ((1 << 23) - 1);
  }
}

__global__ __launch_bounds__(256) void k_stage2(
    const int* __restrict__ in_dst, const int* __restrict__ in_src,
    const int* __restrict__ bb_in, int* __restrict__ ebuf_in,
    const int* __restrict__ has_dst, const int* __restrict__ has_src,
    const int* __restrict__ bb_has, int* __restrict__ ebuf_has) {
  __shared__ int hist[NBK_HAS];
  __shared__ int loff[NBK_HAS];
  __shared__ int gbase[NBK_HAS];
  __shared__ int stg[PT];
  __shared__ int sd[256];
  if (blockIdx.y == 0)
    stage_body<NBK_IN, SHB_IN, SRCB_IN>(in_dst, in_src, bb_in, ebuf_in, hist, loff, gbase,
                                        stg, sd);
  else
    stage_body<NBK_HAS, SHB_HAS, SRCB_HAS>(has_dst, has_src, bb_has, ebuf_has, hist, loff,
                                           gbase, stg, sd);
}

template <int SHB, int SRCB>
__device__ __forceinline__ void place_body(const int* __restrict__ off, int segs,
                                           const int* __restrict__ ebuf,
                                           int* __restrict__ csrc, int* cur) {
  const int NSEG = 1 << SHB;
  int seg0 = blockIdx.x << SHB;
  if (seg0 >= segs) return;  // uniform per block
  int segN = min(seg0 + NSEG, segs);
  for (int i = threadIdx.x; i < segN - seg0; i += 256) cur[i] = off[seg0 + i];
  __syncthreads();
  int start = off[seg0], end = off[segN];
  for (int i = start + threadIdx.x; i < end; i += 256) {
    int v = ebuf[i];
    int dloc = ((u32)v) >> SRCB;
    int pos = atomicAdd(&cur[dloc], 1);
    csrc[pos] = v & ((1 << SRCB) - 1);
  }
}

__global__ __launch_bounds__(256) void k_place2(
    const int* __restrict__ off_in, const int* __restrict__ ebuf_in,
    int* __restrict__ csrc_in, const int* __restrict__ off_has,
    const int* __restrict__ ebuf_has, int* __restrict__ csrc_has) {
  __shared__ int cur[256];
  if (blockIdx.y == 0)
    place_body<SHB_IN, SRCB_IN>(off_in, MCONST, ebuf_in, csrc_in, cur);
  else
    place_body<SHB_HAS, SRCB_HAS>(off_has, NCONST, ebuf_has, csrc_has, cur);
}

// ---------------- online softmax merge helper ----------------
__device__ __forceinline__ void merge_write(float m, float s, float2* __restrict__ pairs) {
  for (int o = 1; o < 64; o <<= 1) {
    float om = __shfl_xor(m, o, 64), os = __shfl_xor(s, o, 64);
    float nm = fmaxf(m, om);
    s = s * __expf(m - nm) + os * __expf(om - nm);
    m = nm;
  }
  __shared__ float sm[4], ss[4];
  int t = threadIdx.x;
  if ((t & 63) == 0) { sm[t >> 6] = m; ss[t >> 6] = s; }
  __syncthreads();
  if (t == 0) {
    for (int k = 1; k < 4; ++k) {
      float nm = fmaxf(m, sm[k]);
      s = s * __expf(m - nm) + ss[k] * __expf(sm[k] - nm);
      m = nm;
    }
    pairs[blockIdx.x] = make_float2(m, s);
  }
}

// ---------------- FC: h = x@W + b (bf16 out), na = h@an, fused softmax1 pair ------------
// IT = float (layer 1) or u16 (layer 2, bf16 bits). SCALE: multiply x by scal_c[4] (=1/S2).
template <typename IT, bool SCALE>
__global__ __launch_bounds__(256, 3) void k_fc(
    const IT* __restrict__ x, const float* __restrict__ W,
    const float* __restrict__ bias, const float* __restrict__ an,
    const int* __restrict__ deg, const float* __restrict__ scal_c,
    u16* __restrict__ h, float* __restrict__ na, float2* __restrict__ pairs, int nrows) {
  __shared__ __align__(16) u16 sWT[128 * 136];
  __shared__ float sNa[128];
  int tid = threadIdx.x;
  int lane = tid & 63, w = tid >> 6;
  int cl = lane & 15, qg = lane >> 4;
  float C = SCALE ? scal_c[4] : 1.0f;

  for (int i = tid * 4; i < 16384; i += 1024) {
    float4 v = *(const float4*)(W + i);
    int k = i >> 7, j = i & 127;
    sWT[(j + 0) * 136 + k] = f2bf(v.x);
    sWT[(j + 1) * 136 + k] = f2bf(v.y);
    sWT[(j + 2) * 136 + k] = f2bf(v.z);
    sWT[(j + 3) * 136 + k] = f2bf(v.w);
  }

  float anv[8], bv[8];
#pragma unroll
  for (int t = 0; t < 8; ++t) {
    anv[t] = an[t * 16 + cl];
    bv[t] = bias[t * 16 + cl];
  }

  int rbase = blockIdx.x * 128 + w * 32;
  bf16x8 afr[2][4];
#pragma unroll
  for (int g = 0; g < 2; ++g) {
    int r = rbase + g * 16 + cl;
    int rc = min(r, nrows - 1);
    const IT* xp = x + (size_t)rc * 128 + qg * 8;
#pragma unroll
    for (int s = 0; s < 4; ++s) {
      if constexpr (sizeof(IT) == 4) {
        float4 u0 = *(const float4*)(xp + s * 32);
        float4 u1 = *(const float4*)(xp + s * 32 + 4);
        bf16x8 a;
        a[0] = (short)f2bf(u0.x); a[1] = (short)f2bf(u0.y);
        a[2] = (short)f2bf(u0.z); a[3] = (short)f2bf(u0.w);
        a[4] = (short)f2bf(u1.x); a[5] = (short)f2bf(u1.y);
        a[6] = (short)f2bf(u1.z); a[7] = (short)f2bf(u1.w);
        afr[g][s] = a;
      } else {
        bf16x8 a = *(const bf16x8*)(xp + s * 32);
        if constexpr (SCALE) {
#pragma unroll
          for (int j = 0; j < 8; ++j) a[j] = (short)f2bf(bf2f((u16)a[j]) * C);
        }
        afr[g][s] = a;
      }
    }
  }
  __syncthreads();

  f32x4 acc[2][8];
#pragma unroll
  for (int g = 0; g < 2; ++g)
#pragma unroll
    for (int t = 0; t < 8; ++t) {
      acc[g][t][0] = 0.f; acc[g][t][1] = 0.f; acc[g][t][2] = 0.f; acc[g][t][3] = 0.f;
    }

#pragma unroll
  for (int t = 0; t < 8; ++t) {
    bf16x8 bfrg[4];
    const u16* bp = sWT + (t * 16 + cl) * 136 + qg * 8;
#pragma unroll
    for (int s = 0; s < 4; ++s) bfrg[s] = *(const bf16x8*)(bp + s * 32);
#pragma unroll
    for (int s = 0; s < 4; ++s) {
#pragma unroll
      for (int g = 0; g < 2; ++g)
        acc[g][t] = __builtin_amdgcn_mfma_f32_16x16x32_bf16(afr[g][s], bfrg[s], acc[g][t],
                                                            0, 0, 0);
    }
  }

  float pa[2][4];
#pragma unroll
  for (int g = 0; g < 2; ++g)
#pragma unroll
    for (int reg = 0; reg < 4; ++reg) pa[g][reg] = 0.f;
#pragma unroll
  for (int g = 0; g < 2; ++g)
#pragma unroll
    for (int t = 0; t < 8; ++t)
#pragma unroll
      for (int reg = 0; reg < 4; ++reg)
        pa[g][reg] = fmaf(acc[g][t][reg] + bv[t], anv[t], pa[g][reg]);
#pragma unroll
  for (int g = 0; g < 2; ++g)
#pragma unroll
    for (int reg = 0; reg < 4; ++reg) {
      float v = pa[g][reg];
      v += __shfl_xor(v, 1, 64);
      v += __shfl_xor(v, 2, 64);
      v += __shfl_xor(v, 4, 64);
      v += __shfl_xor(v, 8, 64);
      pa[g][reg] = v;
    }
  if (cl == 0) {
#pragma unroll
    for (int g = 0; g < 2; ++g)
#pragma unroll
      for (int reg = 0; reg < 4; ++reg) {
        int r = rbase + g * 16 + qg * 4 + reg;
        int lidx = w * 32 + g * 16 + qg * 4 + reg;
        if (r < nrows) {
          na[r] = pa[g][reg];
          sNa[lidx] = pa[g][reg];
        }
      }
  }

  __syncthreads();
  u16* st = sWT + w * 32 * 136;
#pragma unroll
  for (int g = 0; g < 2; ++g)
#pragma unroll
    for (int t = 0; t < 8; ++t)
#pragma unroll
      for (int reg = 0; reg < 4; ++reg)
        st[(g * 16 + qg * 4 + reg) * 136 + t * 16 + cl] = f2bf(acc[g][t][reg] + bv[t]);
#pragma unroll
  for (int it = 0; it < 8; ++it) {
    int idx = it * 64 + lane;
    int row = idx >> 4, c = idx & 15;
    u16x8 v = *(const u16x8*)(st + row * 136 + c * 8);
    int r = rbase + row;
    if (r < nrows) *(u16x8*)(h + (size_t)r * 128 + c * 8) = v;
  }

  // fused softmax1 partial: per-node (m = na, s = deg); block online-merge.
  float m1 = -1e30f, s1 = 0.f;
  if (tid < 128) {
    int r = blockIdx.x * 128 + tid;
    if (r < nrows) {
      int d = deg[r];
      if (d > 0) { m1 = sNa[tid]; s1 = (float)d; }
    }
  }
  merge_write(m1, s1, pairs);
}

__global__ void k_smfin(const float2* __restrict__ pairs, int nb, float* __restrict__ out) {
  int t = threadIdx.x;
  float m = -1e30f, s = 0.f;
  for (int i = t; i < nb; i += 256) {
    float2 pr = pairs[i];
    float nm = fmaxf(m, pr.x);
    s = s * __expf(m - nm) + pr.y * __expf(pr.x - nm);
    m = nm;
  }
  for (int o = 1; o < 64; o <<= 1) {
    float om = __shfl_xor(m, o, 64), os = __shfl_xor(s, o, 64);
    float nm = fmaxf(m, om);
    s = s * __expf(m - nm) + os * __expf(om - nm);
    m = nm;
  }
  __shared__ float sm[4], ss[4];
  if ((t & 63) == 0) { sm[t >> 6] = m; ss[t >> 6] = s; }
  __syncthreads();
  if (t == 0) {
    for (int k = 1; k < 4; ++k) {
      float nm = fmaxf(m, sm[k]);
      s = s * __expf(m - nm) + ss[k] * __expf(sm[k] - nm);
      m = nm;
    }
    out[0] = m;
    out[1] = s;
  }
}

// ---------------- segA (R10 fused form: one wave/segment, 16B/lane, inline exp+ea) ------
__global__ __launch_bounds__(256) void k_segA(
    const u16* __restrict__ h, const float* __restrict__ na,
    const float* __restrict__ scal, const int* __restrict__ csrc,
    const int* __restrict__ off, const float* __restrict__ ae, u16* __restrict__ he,
    float* __restrict__ ea, int m_count) {
  int wid = (blockIdx.x << 2) + (threadIdx.x >> 6);
  if (wid >= m_count) return;
  float mx = scal[0];
  float iz = 1.0f / scal[1];
  int lane = threadIdx.x & 63;
  int sub = lane >> 4, cl = lane & 15;
  int s = off[wid], t = off[wid + 1];
  float ax[8];
#pragma unroll
  for (int j = 0; j < 8; ++j) ax[j] = 0.f;
  for (int i = s + sub; i < t; i += 4) {
    int sr = csrc[i];
    float ww = __expf(na[sr] - mx) * iz;
    u16x8 v = *(const u16x8*)(h + (size_t)sr * 128 + cl * 8);
#pragma unroll
    for (int j = 0; j < 8; ++j) ax[j] = fmaf(ww, bf2f(v[j]), ax[j]);
  }
#pragma unroll
  for (int j = 0; j < 8; ++j) {
    ax[j] += __shfl_xor(ax[j], 16, 64);
    ax[j] += __shfl_xor(ax[j], 32, 64);
  }
  float4 a0 = *(const float4*)(ae + cl * 8);
  float4 a1 = *(const float4*)(ae + cl * 8 + 4);
  float pa = ax[0] * a0.x + ax[1] * a0.y + ax[2] * a0.z + ax[3] * a0.w +
             ax[4] * a1.x + ax[5] * a1.y + ax[6] * a1.z + ax[7] * a1.w;
  pa += __shfl_xor(pa, 1, 64);
  pa += __shfl_xor(pa, 2, 64);
  pa += __shfl_xor(pa, 4, 64);
  pa += __shfl_xor(pa, 8, 64);
  if (sub == 0) {
    u16x8 o;
#pragma unroll
    for (int j = 0; j < 8; ++j) o[j] = f2bf(ax[j]);
    *(u16x8*)(he + (size_t)wid * 128 + cl * 8) = o;
    if (cl == 0) ea[wid] = pa;
  }
}

// softmax2, CSR form (layer 2 only): per node i, online over its has-segment.
__global__ void k_sm2c(const float* __restrict__ na, const float* __restrict__ ea,
                       const int* __restrict__ csrc, const int* __restrict__ off, int n,
                       float2* __restrict__ pairs) {
  float m = -1e30f, s = 0.f;
  int gid = blockIdx.x * 256 + threadIdx.x;
  int stride = gridDim.x * 256;
  for (int i = gid; i < n; i += stride) {
    float nav = na[i];
    int a = off[i], b = off[i + 1];
    for (int j = a; j < b; ++j) {
      float xv = nav + ea[csrc[j]];
      if (xv > m) { s *= __expf(m - xv); m = xv; }
      s += __expf(xv - m);
    }
  }
  merge_write(m, s, pairs);
}

// sum of segB<1>'s S2 partials -> scal[4] = 1/S2
__global__ void k_s2fin(const float2* __restrict__ pairs, int nb, float* __restrict__ out) {
  int t = threadIdx.x;
  float s = 0.f;
  for (int i = t; i < nb; i += 256) s += pairs[i].x;
  for (int o = 1; o < 64; o <<= 1) s += __shfl_xor(s, o, 64);
  __shared__ float sm[4];
  if ((t & 63) == 0) sm[t >> 6] = s;
  __syncthreads();
  if (t == 0) out[4] = 1.0f / (sm[0] + sm[1] + sm[2] + sm[3]);
}

// ---------------- segB (one wave/segment, 16B/lane, 4 edges/iter) ----------------
// L1=1: UNSCALED u = exp(na+ea)*he (relu, bf16 out) + per-block S2 partial -> pairs.
// L1=0: scaled by scal[2,3], fp32 out.
template <int L1>
__global__ __launch_bounds__(256) void k_segB(
    const u16* __restrict__ he, const float* __restrict__ ea,
    const float* __restrict__ na, const float* __restrict__ scal,
    const int* __restrict__ csrc, const int* __restrict__ off,
    void* __restrict__ yout, float2* __restrict__ pairs, int n_count) {
  __shared__ float swv[4];
  int wv = threadIdx.x >> 6;
  int wid = (blockIdx.x << 2) + wv;
  int lane = threadIdx.x & 63;
  int sub = lane >> 4, cl = lane & 15;
  float sx = 0.f;
  if (wid < n_count) {
    float mx2 = L1 ? 0.f : scal[2];
    float iz2 = L1 ? 1.f : (1.0f / scal[3]);
    float nav = na[wid];
    int s = off[wid], t = off[wid + 1];
    float ax[8];
#pragma unroll
    for (int j = 0; j < 8; ++j) ax[j] = 0.f;
    for (int i = s + sub; i < t; i += 4) {
      int sr = csrc[i];
      float c = __expf(ea[sr] + nav - mx2) * iz2;
      if (L1 && cl == 0) sx += c;
      u16x8 v = *(const u16x8*)(he + (size_t)sr * 128 + cl * 8);
#pragma unroll
      for (int j = 0; j < 8; ++j) ax[j] = fmaf(c, bf2f(v[j]), ax[j]);
    }
#pragma unroll
    for (int j = 0; j < 8; ++j) {
      ax[j] += __shfl_xor(ax[j], 16, 64);
      ax[j] += __shfl_xor(ax[j], 32, 64);
      if (L1) ax[j] = fmaxf(ax[j], 0.f);
    }
    if (sub == 0) {
      if (L1) {
        u16x8 o;
#pragma unroll
        for (int j = 0; j < 8; ++j) o[j] = f2bf(ax[j]);
        *(u16x8*)((u16*)yout + (size_t)wid * 128 + cl * 8) = o;
      } else {
        float4 A = make_float4(ax[0], ax[1], ax[2], ax[3]);
        float4 B = make_float4(ax[4], ax[5], ax[6], ax[7]);
        float* y = (float*)yout;
        *(float4*)(y + (size_t)wid * 128 + cl * 8) = A;
        *(float4*)(y + (size_t)wid * 128 + cl * 8 + 4) = B;
      }
    }
  }
  if (L1) {
    for (int o = 1; o < 64; o <<= 1) sx += __shfl_xor(sx, o, 64);
    if (lane == 0) swv[wv] = sx;
    __syncthreads();
    if (threadIdx.x == 0)
      pairs[blockIdx.x] = make_float2(swv[0] + swv[1] + swv[2] + swv[3], 0.f);
  }
}

// ---------------- host ----------------
extern "C" void kernel_launch(void* const* d_in, const int* in_sizes, int n_in,
                              void* d_out, int out_size, void* d_ws, size_t ws_size,
                              hipStream_t stream) {
  const int N = NCONST, M = MCONST, E = ECONST;
  const float* x = (const float*)d_in[0];
  const int* in_src = (const int*)d_in[1];
  const int* in_dst = (const int*)d_in[2];
  const int* has_src = (const int*)d_in[3];
  const int* has_dst = (const int*)d_in[4];
  const float* W1 = (const float*)d_in[5];
  const float* b1 = (const float*)d_in[6];
  const float* an1 = (const float*)d_in[7];
  const float* ae1 = (const float*)d_in[8];
  const float* W2 = (const float*)d_in[9];
  const float* b2 = (const float*)d_in[10];
  const float* an2 = (const float*)d_in[11];
  const float* ae2 = (const float*)d_in[12];

  const size_t PARTIAL_BYTES = (size_t)9 * HBC * HCH2 * 4;  // 37.7 MB

  char* p = (char*)d_ws;
  auto alloc = [&](size_t bytes) {
    char* q = p;
    p += (bytes + 255) & ~(size_t)255;
    return q;
  };
  u16* h = (u16*)alloc((size_t)N * 128 * 2);
  u16* he = (u16*)alloc((size_t)M * 128 * 2);
  float* na = (float*)alloc((size_t)N * 4);
  float* ea = (float*)alloc((size_t)M * 4);
  int* deg = (int*)alloc((size_t)N * 4);
  int* off_in = (int*)alloc((size_t)(M + 1) * 4);
  int* off_has = (int*)alloc((size_t)(N + 1) * 4);
  int* csrc_in = (int*)alloc((size_t)E * 4);
  int* csrc_has = (int*)alloc((size_t)E * 4);
  int* partial = (int*)alloc(PARTIAL_BYTES);  // unions with ebufs (disjoint lifetime)
  int* ebuf_in = partial;
  int* ebuf_has = partial + ECONST;
  int* bb_in = (int*)alloc((size_t)PBLK * NBK_IN * 4);
  int* bb_has = (int*)alloc((size_t)PBLK * NBK_HAS * 4);
  int* bsum = (int*)alloc(256 * 4);
  float2* pairs = (float2*)alloc((size_t)25600 * 8);
  float* scal = (float*)alloc(64);
  if ((size_t)(p - (char*)d_ws) > ws_size) return;  // insufficient workspace

  u16* y1b = (u16*)d_out;  // layer-1 bf16 (UNSCALED) output staged in d_out bytes;
                           // fc2 scales by scal[4]=1/S2; final fp32 overwrites in segB<0>.

  // histograms (one launch) + merged scans (+ deg reduction as y=2)
  k_hpart2<<<dim3(HBC, 9), 256, 0, stream>>>(in_dst, has_dst, in_src, partial);
  int nbM = (M + 1023) / 1024, nbN = (N + 1023) / 1024;
  k_scan1d<<<dim3(nbN, 3), 256, 0, stream>>>(partial, M, N, off_in, off_has, deg, bsum);
  k_scan2d<<<2, 256, 0, stream>>>(bsum, nbM, nbN);
  k_scan3d<<<dim3(512, 2), 256, 0, stream>>>(off_in, off_has, bsum, M, N);

  // scatter v3 (atomic-free partition), directions merged via blockIdx.y
  k_coarse<<<PBLK, 256, 0, stream>>>(in_dst, has_dst, bb_in, bb_has);
  k_colscan2<<<dim3(NBK_HAS, 2), 256, 0, stream>>>(bb_in, off_in, bb_has, off_has);
  k_stage2<<<dim3(PBLK, 2), 256, 0, stream>>>(in_dst, in_src, bb_in, ebuf_in, has_dst,
                                              has_src, bb_has, ebuf_has);
  k_place2<<<dim3(NBK_HAS, 2), 256, 0, stream>>>(off_in, ebuf_in, csrc_in, off_has,
                                                 ebuf_has, csrc_has);

  const int FCB = (N + 127) / 128;  // 782 fc blocks
  const int SGB = (M + 3) / 4;      // segA blocks
  const int SBB = (N + 3) / 4;      // segB blocks

  // ---- layer 1 ----
  k_fc<float, false><<<FCB, 256, 0, stream>>>(x, W1, b1, an1, deg, scal, h, na, pairs, N);
  k_smfin<<<1, 256, 0, stream>>>(pairs, FCB, scal);  // scal[0,1] = mx1, S1
  k_segA<<<SGB, 256, 0, stream>>>(h, na, scal, csrc_in, off_in, ae1, he, ea, M);
  k_segB<1><<<SBB, 256, 0, stream>>>(he, ea, na, scal, csrc_has, off_has, (void*)y1b,
                                     pairs, N);
  k_s2fin<<<1, 256, 0, stream>>>(pairs, SBB, scal);  // scal[4] = 1/S2

  // ---- layer 2 ----
  k_fc<u16, true><<<FCB, 256, 0, stream>>>(y1b, W2, b2, an2, deg, scal, h, na, pairs, N);
  k_smfin<<<1, 256, 0, stream>>>(pairs, FCB, scal);  // scal[0,1] for layer 2
  k_segA<<<SGB, 256, 0, stream>>>(h, na, scal, csrc_in, off_in, ae2, he, ea, M);
  k_sm2c<<<128, 256, 0, stream>>>(na, ea, csrc_has, off_has, N, pairs);
  k_smfin<<<1, 256, 0, stream>>>(pairs, 128, scal + 2);  // scal[2,3]
  k_segB<0><<<SBB, 256, 0, stream>>>(he, ea, na, scal, csrc_has, off_has, d_out, pairs, N);
}

// Round 14
// 450.882 us; speedup vs baseline: 1.6320x; 1.1164x over previous
//
#include <hip/hip_runtime.h>
#include <hip/hip_bf16.h>
#include <math.h>
#include <type_traits>

// HGAT: 2-layer hypergraph attention. N nodes, M hyperedges, E incidence edges, D=128.
// R14: revert to R10 structure (471us proven; R13's pass-reshuffles were net-negative).
// ONE change: segA/segB use 8-edge-slot x 8-lane layout (was 4x16): 8 edges & 16 loads
// in flight per wave-iter (vs 4/4), redundant per-edge exp halved. Both kernels are
// latency-bound on compulsory cross-XCD L2 fill (segA 180MB=8x0.86x25.6MB h; segB
// 79MB~8x5MB he) — more MLP is the only remaining lever.
// Scatter v3 (R8), MFMA fc + fused softmax1 (R10), bf16 rows (R3).

typedef unsigned int u32;
typedef unsigned short u16;
typedef u16 u16x8 __attribute__((ext_vector_type(8)));
typedef short bf16x8 __attribute__((ext_vector_type(8)));
typedef float f32x4 __attribute__((ext_vector_type(4)));

#define NCONST 100000
#define MCONST 20000
#define ECONST 1600000
#define HCH2 32768  // histogram chunk (ints) = 128KB LDS
#define HBC 32      // blocks per chunk

#define PBLK 256        // partition blocks (1 chunk each)
#define PT 6250         // edges per partition chunk (E/PBLK)
#define SHB_IN 6        // coarse bucket shift, in-direction
#define NBK_IN 313      // ceil(M / 64)
#define SRCB_IN 17      // src bits (in_src < 2^17)
#define SHB_HAS 8       // coarse bucket shift, has-direction
#define NBK_HAS 391     // ceil(N / 256)
#define SRCB_HAS 15     // src bits (has_src < 2^15)

__device__ __forceinline__ u16 f2bf(float f) {  // RNE
  u32 u = __float_as_uint(f);
  u += 0x7FFFu + ((u >> 16) & 1u);
  return (u16)(u >> 16);
}
__device__ __forceinline__ float bf2f(u16 b) {
  return __uint_as_float(((u32)b) << 16);
}

// ---------------- histograms: one launch, LDS-private, no global atomics ----------------
// grid (HBC, 9): y=0 -> in_dst (M); y=1..4 -> has_dst chunks; y=5..8 -> in_src chunks.
__global__ __launch_bounds__(256) void k_hpart2(const int* __restrict__ in_dst,
                                                const int* __restrict__ has_dst,
                                                const int* __restrict__ in_src,
                                                int* __restrict__ partial) {
  __shared__ int hc[HCH2];
  int y = blockIdx.y;
  const int* __restrict__ arr = (y == 0) ? in_dst : (y <= 4 ? has_dst : in_src);
  int lo = (y == 0) ? 0 : (y <= 4 ? (y - 1) * HCH2 : (y - 5) * HCH2);
  for (int i = threadIdx.x; i < HCH2; i += 256) hc[i] = 0;
  __syncthreads();
  int stride = gridDim.x * 256;
  int n4 = ECONST >> 2;
  const int4* a4 = (const int4*)arr;
  for (int i = blockIdx.x * 256 + threadIdx.x; i < n4; i += stride) {
    int4 v = a4[i];
    u32 a = (u32)(v.x - lo), b = (u32)(v.y - lo), c = (u32)(v.z - lo), d = (u32)(v.w - lo);
    if (a < HCH2) atomicAdd(&hc[a], 1);
    if (b < HCH2) atomicAdd(&hc[b], 1);
    if (c < HCH2) atomicAdd(&hc[c], 1);
    if (d < HCH2) atomicAdd(&hc[d], 1);
  }
  __syncthreads();
  int* out = partial + ((size_t)y * HBC + blockIdx.x) * HCH2;
  for (int i = threadIdx.x; i < HCH2; i += 256) out[i] = hc[i];
}

// ---------------- scans: y=0 -> off_in (M), y=1 -> off_has (N), y=2 -> deg (raw sums)
__global__ void k_scan1d(const int* __restrict__ partial, int nM, int nN,
                         int* __restrict__ off_in, int* __restrict__ off_has,
                         int* __restrict__ deg, int* __restrict__ bsum) {
  __shared__ int sd[256];
  int y = blockIdx.y;
  int n = y ? nN : nM;
  int rowbase = (y == 0) ? 0 : (y == 1 ? 1 : 5);
  int t = threadIdx.x;
  int base = blockIdx.x * 1024 + t * 4;
  int v[4];
#pragma unroll
  for (int k = 0; k < 4; ++k) {
    int j = base + k;
    int s = 0;
    if (j < n) {
      int chunk = j >> 15;
      int jl = j & (HCH2 - 1);
      const int* p = partial + ((size_t)(rowbase + chunk) * HBC) * HCH2 + jl;
#pragma unroll
      for (int b = 0; b < HBC; ++b) s += p[(size_t)b * HCH2];
    }
    v[k] = s;
  }
  if (y == 2) {
#pragma unroll
    for (int k = 0; k < 4; ++k)
      if (base + k < n) deg[base + k] = v[k];
    return;
  }
  int* off = y ? off_has : off_in;
  int* bs = bsum + y * 128;
  v[1] += v[0]; v[2] += v[1]; v[3] += v[2];
  int tot = v[3];
  sd[t] = tot;
  __syncthreads();
  for (int o = 1; o < 256; o <<= 1) {
    int x = (t >= o) ? sd[t - o] : 0;
    __syncthreads();
    sd[t] += x;
    __syncthreads();
  }
  int excl = sd[t] - tot;
#pragma unroll
  for (int k = 0; k < 4; ++k)
    if (base + k < n) off[base + k + 1] = v[k] + excl;
  if (t == 255) bs[blockIdx.x] = sd[255];
}

__global__ void k_scan2d(int* __restrict__ bsum, int nbM, int nbN) {
  __shared__ int sd[256];
  int* bs = bsum + blockIdx.x * 128;
  int nb = blockIdx.x ? nbN : nbM;
  int t = threadIdx.x;
  int v = (t < nb) ? bs[t] : 0;
  sd[t] = v;
  __syncthreads();
  for (int o = 1; o < 256; o <<= 1) {
    int x = (t >= o) ? sd[t - o] : 0;
    __syncthreads();
    sd[t] += x;
    __syncthreads();
  }
  if (t < nb) bs[t] = sd[t] - v;  // exclusive
}

__global__ void k_scan3d(int* __restrict__ off_in, int* __restrict__ off_has,
                         const int* __restrict__ bsum, int nM, int nN) {
  int y = blockIdx.y;
  int* off = y ? off_has : off_in;
  const int* bs = bsum + y * 128;
  int n = y ? nN : nM;
  int i = blockIdx.x * blockDim.x + threadIdx.x;
  int st = gridDim.x * blockDim.x;
  if (blockIdx.x == 0 && threadIdx.x == 0) off[0] = 0;
  for (; i < n; i += st) off[i + 1] += bs[i >> 10];
}

// ---------------- scatter v3: atomic-free LDS-staged partition ----------------
__global__ __launch_bounds__(256) void k_coarse(const int* __restrict__ in_dst,
                                                const int* __restrict__ has_dst,
                                                int* __restrict__ bb_in,
                                                int* __restrict__ bb_has) {
  __shared__ int h1[NBK_IN];
  __shared__ int h2[NBK_HAS];
  for (int i = threadIdx.x; i < NBK_IN; i += 256) h1[i] = 0;
  for (int i = threadIdx.x; i < NBK_HAS; i += 256) h2[i] = 0;
  __syncthreads();
  int c0 = blockIdx.x * PT, c1 = min(c0 + PT, ECONST);
  for (int i = c0 + threadIdx.x; i < c1; i += 256) {
    atomicAdd(&h1[in_dst[i] >> SHB_IN], 1);
    atomicAdd(&h2[has_dst[i] >> SHB_HAS], 1);
  }
  __syncthreads();
  int* o1 = bb_in + (size_t)blockIdx.x * NBK_IN;
  for (int i = threadIdx.x; i < NBK_IN; i += 256) o1[i] = h1[i];
  int* o2 = bb_has + (size_t)blockIdx.x * NBK_HAS;
  for (int i = threadIdx.x; i < NBK_HAS; i += 256) o2[i] = h2[i];
}

template <int NBUK, int SHB>
__device__ __forceinline__ void colscan_body(int* __restrict__ bb,
                                             const int* __restrict__ off, int segs,
                                             int* sd) {
  int b = blockIdx.x;
  if (b >= NBUK) return;  // uniform per block
  int t = threadIdx.x;
  int v = bb[(size_t)t * NBUK + b];
  sd[t] = v;
  __syncthreads();
  for (int o = 1; o < 256; o <<= 1) {
    int x = (t >= o) ? sd[t - o] : 0;
    __syncthreads();
    sd[t] += x;
    __syncthreads();
  }
  bb[(size_t)t * NBUK + b] = sd[t] - v + off[min(b << SHB, segs)];
}

__global__ __launch_bounds__(256) void k_colscan2(int* __restrict__ bb_in,
                                                  const int* __restrict__ off_in,
                                                  int* __restrict__ bb_has,
                                                  const int* __restrict__ off_has) {
  __shared__ int sd[256];
  if (blockIdx.y == 0)
    colscan_body<NBK_IN, SHB_IN>(bb_in, off_in, MCONST, sd);
  else
    colscan_body<NBK_HAS, SHB_HAS>(bb_has, off_has, NCONST, sd);
}

template <int NBUK, int SHB, int SRCB>
__device__ __forceinline__ void stage_body(const int* __restrict__ dst,
                                           const int* __restrict__ srcv,
                                           const int* __restrict__ bb,
                                           int* __restrict__ ebuf, int* hist, int* loff,
                                           int* gbase, int* stg, int* sd) {
  int t = threadIdx.x;
  for (int i = t; i < NBUK; i += 256) hist[i] = 0;
  __syncthreads();
  int c0 = blockIdx.x * PT, c1 = min(c0 + PT, ECONST);
  for (int i = c0 + t; i < c1; i += 256) atomicAdd(&hist[dst[i] >> SHB], 1);
  __syncthreads();
  {
    int v0 = (2 * t < NBUK) ? hist[2 * t] : 0;
    int v1 = (2 * t + 1 < NBUK) ? hist[2 * t + 1] : 0;
    sd[t] = v0 + v1;
    __syncthreads();
    for (int o = 1; o < 256; o <<= 1) {
      int x = (t >= o) ? sd[t - o] : 0;
      __syncthreads();
      sd[t] += x;
      __syncthreads();
    }
    int excl = sd[t] - (v0 + v1);
    if (2 * t < NBUK) loff[2 * t] = excl;
    if (2 * t + 1 < NBUK) loff[2 * t + 1] = excl + v0;
  }
  __syncthreads();
  for (int i = t; i < NBUK; i += 256) {
    gbase[i] = bb[(size_t)blockIdx.x * NBUK + i];
    hist[i] = loff[i];  // cursor
  }
  __syncthreads();
  for (int i = c0 + t; i < c1; i += 256) {
    int d = dst[i], s = srcv[i];
    int b = d >> SHB;
    int r = atomicAdd(&hist[b], 1);
    stg[r] = (b << 23) | ((d & ((1 << SHB) - 1)) << SRCB) | s;
  }
  __syncthreads();
  int tot = c1 - c0;
  for (int i = t; i < tot; i += 256) {
    int v = stg[i];
    int b = ((u32)v) >> 23;
    ebuf[gbase[b] + (i - loff[b])] = v & ((1 << 23) - 1);
  }
}

__global__ __launch_bounds__(256) void k_stage2(
    const int* __restrict__ in_dst, const int* __restrict__ in_src,
    const int* __restrict__ bb_in, int* __restrict__ ebuf_in,
    const int* __restrict__ has_dst, const int* __restrict__ has_src,
    const int* __restrict__ bb_has, int* __restrict__ ebuf_has) {
  __shared__ int hist[NBK_HAS];
  __shared__ int loff[NBK_HAS];
  __shared__ int gbase[NBK_HAS];
  __shared__ int stg[PT];
  __shared__ int sd[256];
  if (blockIdx.y == 0)
    stage_body<NBK_IN, SHB_IN, SRCB_IN>(in_dst, in_src, bb_in, ebuf_in, hist, loff, gbase,
                                        stg, sd);
  else
    stage_body<NBK_HAS, SHB_HAS, SRCB_HAS>(has_dst, has_src, bb_has, ebuf_has, hist, loff,
                                           gbase, stg, sd);
}

template <int SHB, int SRCB>
__device__ __forceinline__ void place_body(const int* __restrict__ off, int segs,
                                           const int* __restrict__ ebuf,
                                           int* __restrict__ csrc, int* cur) {
  const int NSEG = 1 << SHB;
  int seg0 = blockIdx.x << SHB;
  if (seg0 >= segs) return;  // uniform per block
  int segN = min(seg0 + NSEG, segs);
  for (int i = threadIdx.x; i < segN - seg0; i += 256) cur[i] = off[seg0 + i];
  __syncthreads();
  int start = off[seg0], end = off[segN];
  for (int i = start + threadIdx.x; i < end; i += 256) {
    int v = ebuf[i];
    int dloc = ((u32)v) >> SRCB;
    int pos = atomicAdd(&cur[dloc], 1);
    csrc[pos] = v & ((1 << SRCB) - 1);
  }
}

__global__ __launch_bounds__(256) void k_place2(
    const int* __restrict__ off_in, const int* __restrict__ ebuf_in,
    int* __restrict__ csrc_in, const int* __restrict__ off_has,
    const int* __restrict__ ebuf_has, int* __restrict__ csrc_has) {
  __shared__ int cur[256];
  if (blockIdx.y == 0)
    place_body<SHB_IN, SRCB_IN>(off_in, MCONST, ebuf_in, csrc_in, cur);
  else
    place_body<SHB_HAS, SRCB_HAS>(off_has, NCONST, ebuf_has, csrc_has, cur);
}

// ---------------- online softmax merge helper ----------------
__device__ __forceinline__ void merge_write(float m, float s, float2* __restrict__ pairs) {
  for (int o = 1; o < 64; o <<= 1) {
    float om = __shfl_xor(m, o, 64), os = __shfl_xor(s, o, 64);
    float nm = fmaxf(m, om);
    s = s * __expf(m - nm) + os * __expf(om - nm);
    m = nm;
  }
  __shared__ float sm[4], ss[4];
  int t = threadIdx.x;
  if ((t & 63) == 0) { sm[t >> 6] = m; ss[t >> 6] = s; }
  __syncthreads();
  if (t == 0) {
    for (int k = 1; k < 4; ++k) {
      float nm = fmaxf(m, sm[k]);
      s = s * __expf(m - nm) + ss[k] * __expf(sm[k] - nm);
      m = nm;
    }
    pairs[blockIdx.x] = make_float2(m, s);
  }
}

// ---------------- FC: h = x@W + b (bf16 out), na = h@an, fused softmax1 pair ------------
// IT = float (layer 1) or u16 (layer 2, bf16 bits direct).
template <typename IT>
__global__ __launch_bounds__(256, 3) void k_fc(
    const IT* __restrict__ x, const float* __restrict__ W,
    const float* __restrict__ bias, const float* __restrict__ an,
    const int* __restrict__ deg, u16* __restrict__ h, float* __restrict__ na,
    float2* __restrict__ pairs, int nrows) {
  __shared__ __align__(16) u16 sWT[128 * 136];
  __shared__ float sNa[128];
  int tid = threadIdx.x;
  int lane = tid & 63, w = tid >> 6;
  int cl = lane & 15, qg = lane >> 4;

  for (int i = tid * 4; i < 16384; i += 1024) {
    float4 v = *(const float4*)(W + i);
    int k = i >> 7, j = i & 127;
    sWT[(j + 0) * 136 + k] = f2bf(v.x);
    sWT[(j + 1) * 136 + k] = f2bf(v.y);
    sWT[(j + 2) * 136 + k] = f2bf(v.z);
    sWT[(j + 3) * 136 + k] = f2bf(v.w);
  }

  float anv[8], bv[8];
#pragma unroll
  for (int t = 0; t < 8; ++t) {
    anv[t] = an[t * 16 + cl];
    bv[t] = bias[t * 16 + cl];
  }

  int rbase = blockIdx.x * 128 + w * 32;
  bf16x8 afr[2][4];
#pragma unroll
  for (int g = 0; g < 2; ++g) {
    int r = rbase + g * 16 + cl;
    int rc = min(r, nrows - 1);
    const IT* xp = x + (size_t)rc * 128 + qg * 8;
#pragma unroll
    for (int s = 0; s < 4; ++s) {
      if constexpr (sizeof(IT) == 4) {
        float4 u0 = *(const float4*)(xp + s * 32);
        float4 u1 = *(const float4*)(xp + s * 32 + 4);
        bf16x8 a;
        a[0] = (short)f2bf(u0.x); a[1] = (short)f2bf(u0.y);
        a[2] = (short)f2bf(u0.z); a[3] = (short)f2bf(u0.w);
        a[4] = (short)f2bf(u1.x); a[5] = (short)f2bf(u1.y);
        a[6] = (short)f2bf(u1.z); a[7] = (short)f2bf(u1.w);
        afr[g][s] = a;
      } else {
        afr[g][s] = *(const bf16x8*)(xp + s * 32);
      }
    }
  }
  __syncthreads();

  f32x4 acc[2][8];
#pragma unroll
  for (int g = 0; g < 2; ++g)
#pragma unroll
    for (int t = 0; t < 8; ++t) {
      acc[g][t][0] = 0.f; acc[g][t][1] = 0.f; acc[g][t][2] = 0.f; acc[g][t][3] = 0.f;
    }

#pragma unroll
  for (int t = 0; t < 8; ++t) {
    bf16x8 bfrg[4];
    const u16* bp = sWT + (t * 16 + cl) * 136 + qg * 8;
#pragma unroll
    for (int s = 0; s < 4; ++s) bfrg[s] = *(const bf16x8*)(bp + s * 32);
#pragma unroll
    for (int s = 0; s < 4; ++s) {
#pragma unroll
      for (int g = 0; g < 2; ++g)
        acc[g][t] = __builtin_amdgcn_mfma_f32_16x16x32_bf16(afr[g][s], bfrg[s], acc[g][t],
                                                            0, 0, 0);
    }
  }

  float pa[2][4];
#pragma unroll
  for (int g = 0; g < 2; ++g)
#pragma unroll
    for (int reg = 0; reg < 4; ++reg) pa[g][reg] = 0.f;
#pragma unroll
  for (int g = 0; g < 2; ++g)
#pragma unroll
    for (int t = 0; t < 8; ++t)
#pragma unroll
      for (int reg = 0; reg < 4; ++reg)
        pa[g][reg] = fmaf(acc[g][t][reg] + bv[t], anv[t], pa[g][reg]);
#pragma unroll
  for (int g = 0; g < 2; ++g)
#pragma unroll
    for (int reg = 0; reg < 4; ++reg) {
      float v = pa[g][reg];
      v += __shfl_xor(v, 1, 64);
      v += __shfl_xor(v, 2, 64);
      v += __shfl_xor(v, 4, 64);
      v += __shfl_xor(v, 8, 64);
      pa[g][reg] = v;
    }
  if (cl == 0) {
#pragma unroll
    for (int g = 0; g < 2; ++g)
#pragma unroll
      for (int reg = 0; reg < 4; ++reg) {
        int r = rbase + g * 16 + qg * 4 + reg;
        int lidx = w * 32 + g * 16 + qg * 4 + reg;
        if (r < nrows) {
          na[r] = pa[g][reg];
          sNa[lidx] = pa[g][reg];
        }
      }
  }

  __syncthreads();
  u16* st = sWT + w * 32 * 136;
#pragma unroll
  for (int g = 0; g < 2; ++g)
#pragma unroll
    for (int t = 0; t < 8; ++t)
#pragma unroll
      for (int reg = 0; reg < 4; ++reg)
        st[(g * 16 + qg * 4 + reg) * 136 + t * 16 + cl] = f2bf(acc[g][t][reg] + bv[t]);
#pragma unroll
  for (int it = 0; it < 8; ++it) {
    int idx = it * 64 + lane;
    int row = idx >> 4, c = idx & 15;
    u16x8 v = *(const u16x8*)(st + row * 136 + c * 8);
    int r = rbase + row;
    if (r < nrows) *(u16x8*)(h + (size_t)r * 128 + c * 8) = v;
  }

  // fused softmax1 partial: per-node (m = na, s = deg); block online-merge.
  float m1 = -1e30f, s1 = 0.f;
  if (tid < 128) {
    int r = blockIdx.x * 128 + tid;
    if (r < nrows) {
      int d = deg[r];
      if (d > 0) { m1 = sNa[tid]; s1 = (float)d; }
    }
  }
  merge_write(m1, s1, pairs);
}

// ---------------- softmax2 single online pass over E ----------------
__global__ void k_sm2(const float* __restrict__ ea, const float* __restrict__ na,
                      const int* __restrict__ hs, const int* __restrict__ hd, int n,
                      float2* __restrict__ pairs) {
  float m = -1e30f, s = 0.f;
  int i = blockIdx.x * blockDim.x + threadIdx.x;
  int st = gridDim.x * blockDim.x;
  for (; i < n; i += st) {
    float xv = ea[hs[i]] + na[hd[i]];
    if (xv > m) { s *= __expf(m - xv); m = xv; }
    s += __expf(xv - m);
  }
  merge_write(m, s, pairs);
}

__global__ void k_smfin(const float2* __restrict__ pairs, int nb, float* __restrict__ out) {
  int t = threadIdx.x;
  float m = -1e30f, s = 0.f;
  for (int i = t; i < nb; i += 256) {
    float2 pr = pairs[i];
    float nm = fmaxf(m, pr.x);
    s = s * __expf(m - nm) + pr.y * __expf(pr.x - nm);
    m = nm;
  }
  for (int o = 1; o < 64; o <<= 1) {
    float om = __shfl_xor(m, o, 64), os = __shfl_xor(s, o, 64);
    float nm = fmaxf(m, om);
    s = s * __expf(m - nm) + os * __expf(om - nm);
    m = nm;
  }
  __shared__ float sm[4], ss[4];
  if ((t & 63) == 0) { sm[t >> 6] = m; ss[t >> 6] = s; }
  __syncthreads();
  if (t == 0) {
    for (int k = 1; k < 4; ++k) {
      float nm = fmaxf(m, sm[k]);
      s = s * __expf(m - nm) + ss[k] * __expf(sm[k] - nm);
      m = nm;
    }
    out[0] = m;
    out[1] = s;
  }
}

// ---------------- segA: one wave/segment, 8 edge-slots x 8 lanes (32B/lane) -------------
__global__ __launch_bounds__(256) void k_segA(
    const u16* __restrict__ h, const float* __restrict__ na,
    const float* __restrict__ scal, const int* __restrict__ csrc,
    const int* __restrict__ off, const float* __restrict__ ae, u16* __restrict__ he,
    float* __restrict__ ea, int m_count) {
  int wid = (blockIdx.x << 2) + (threadIdx.x >> 6);
  if (wid >= m_count) return;
  float mx = scal[0];
  float iz = 1.0f / scal[1];
  int lane = threadIdx.x & 63;
  int eslot = lane >> 3, cl = lane & 7;
  int s = off[wid], t = off[wid + 1];
  float ax[16];
#pragma unroll
  for (int j = 0; j < 16; ++j) ax[j] = 0.f;
  for (int i = s + eslot; i < t; i += 8) {
    int sr = csrc[i];
    float ww = __expf(na[sr] - mx) * iz;
    const u16* hp = h + (size_t)sr * 128 + cl * 16;
    u16x8 v0 = *(const u16x8*)(hp);
    u16x8 v1 = *(const u16x8*)(hp + 8);
#pragma unroll
    for (int j = 0; j < 8; ++j) {
      ax[j] = fmaf(ww, bf2f(v0[j]), ax[j]);
      ax[8 + j] = fmaf(ww, bf2f(v1[j]), ax[8 + j]);
    }
  }
#pragma unroll
  for (int j = 0; j < 16; ++j) {
    ax[j] += __shfl_xor(ax[j], 8, 64);
    ax[j] += __shfl_xor(ax[j], 16, 64);
    ax[j] += __shfl_xor(ax[j], 32, 64);
  }
  const float* aep = ae + cl * 16;
  float pa = 0.f;
#pragma unroll
  for (int j = 0; j < 16; ++j) pa = fmaf(ax[j], aep[j], pa);
  pa += __shfl_xor(pa, 1, 64);
  pa += __shfl_xor(pa, 2, 64);
  pa += __shfl_xor(pa, 4, 64);
  if (eslot == 0) {
    u16x8 o0, o1;
#pragma unroll
    for (int j = 0; j < 8; ++j) { o0[j] = f2bf(ax[j]); o1[j] = f2bf(ax[8 + j]); }
    u16* hep = he + (size_t)wid * 128 + cl * 16;
    *(u16x8*)(hep) = o0;
    *(u16x8*)(hep + 8) = o1;
    if (cl == 0) ea[wid] = pa;
  }
}

// ---------------- segB: one wave/segment, 8 edge-slots x 8 lanes (32B/lane) -------------
// L1=1: scaled + relu + bf16 out; L1=0: scaled fp32 out.
template <int L1>
__global__ __launch_bounds__(256) void k_segB(
    const u16* __restrict__ he, const float* __restrict__ ea,
    const float* __restrict__ na, const float* __restrict__ scal,
    const int* __restrict__ csrc, const int* __restrict__ off,
    void* __restrict__ yout, int n_count) {
  int wid = (blockIdx.x << 2) + (threadIdx.x >> 6);
  if (wid >= n_count) return;
  float mx2 = scal[2];
  float iz2 = 1.0f / scal[3];
  int lane = threadIdx.x & 63;
  int eslot = lane >> 3, cl = lane & 7;
  float nav = na[wid];
  int s = off[wid], t = off[wid + 1];
  float ax[16];
#pragma unroll
  for (int j = 0; j < 16; ++j) ax[j] = 0.f;
  for (int i = s + eslot; i < t; i += 8) {
    int sr = csrc[i];
    float c = __expf(ea[sr] + nav - mx2) * iz2;
    const u16* hp = he + (size_t)sr * 128 + cl * 16;
    u16x8 v0 = *(const u16x8*)(hp);
    u16x8 v1 = *(const u16x8*)(hp + 8);
#pragma unroll
    for (int j = 0; j < 8; ++j) {
      ax[j] = fmaf(c, bf2f(v0[j]), ax[j]);
      ax[8 + j] = fmaf(c, bf2f(v1[j]), ax[8 + j]);
    }
  }
#pragma unroll
  for (int j = 0; j < 16; ++j) {
    ax[j] += __shfl_xor(ax[j], 8, 64);
    ax[j] += __shfl_xor(ax[j], 16, 64);
    ax[j] += __shfl_xor(ax[j], 32, 64);
    if (L1) ax[j] = fmaxf(ax[j], 0.f);
  }
  if (eslot == 0) {
    if (L1) {
      u16x8 o0, o1;
#pragma unroll
      for (int j = 0; j < 8; ++j) { o0[j] = f2bf(ax[j]); o1[j] = f2bf(ax[8 + j]); }
      u16* yp = (u16*)yout + (size_t)wid * 128 + cl * 16;
      *(u16x8*)(yp) = o0;
      *(u16x8*)(yp + 8) = o1;
    } else {
      float* y = (float*)yout + (size_t)wid * 128 + cl * 16;
      *(float4*)(y + 0) = make_float4(ax[0], ax[1], ax[2], ax[3]);
      *(float4*)(y + 4) = make_float4(ax[4], ax[5], ax[6], ax[7]);
      *(float4*)(y + 8) = make_float4(ax[8], ax[9], ax[10], ax[11]);
      *(float4*)(y + 12) = make_float4(ax[12], ax[13], ax[14], ax[15]);
    }
  }
}

// ---------------- host ----------------
extern "C" void kernel_launch(void* const* d_in, const int* in_sizes, int n_in,
                              void* d_out, int out_size, void* d_ws, size_t ws_size,
                              hipStream_t stream) {
  const int N = NCONST, M = MCONST, E = ECONST;
  const float* x = (const float*)d_in[0];
  const int* in_src = (const int*)d_in[1];
  const int* in_dst = (const int*)d_in[2];
  const int* has_src = (const int*)d_in[3];
  const int* has_dst = (const int*)d_in[4];
  const float* W1 = (const float*)d_in[5];
  const float* b1 = (const float*)d_in[6];
  const float* an1 = (const float*)d_in[7];
  const float* ae1 = (const float*)d_in[8];
  const float* W2 = (const float*)d_in[9];
  const float* b2 = (const float*)d_in[10];
  const float* an2 = (const float*)d_in[11];
  const float* ae2 = (const float*)d_in[12];

  const size_t PARTIAL_BYTES = (size_t)9 * HBC * HCH2 * 4;  // 37.7 MB

  char* p = (char*)d_ws;
  auto alloc = [&](size_t bytes) {
    char* q = p;
    p += (bytes + 255) & ~(size_t)255;
    return q;
  };
  u16* h = (u16*)alloc((size_t)N * 128 * 2);
  u16* he = (u16*)alloc((size_t)M * 128 * 2);
  float* na = (float*)alloc((size_t)N * 4);
  float* ea = (float*)alloc((size_t)M * 4);
  int* deg = (int*)alloc((size_t)N * 4);
  int* off_in = (int*)alloc((size_t)(M + 1) * 4);
  int* off_has = (int*)alloc((size_t)(N + 1) * 4);
  int* csrc_in = (int*)alloc((size_t)E * 4);
  int* csrc_has = (int*)alloc((size_t)E * 4);
  int* partial = (int*)alloc(PARTIAL_BYTES);  // unions with ebufs (disjoint lifetime)
  int* ebuf_in = partial;
  int* ebuf_has = partial + ECONST;
  int* bb_in = (int*)alloc((size_t)PBLK * NBK_IN * 4);
  int* bb_has = (int*)alloc((size_t)PBLK * NBK_HAS * 4);
  int* bsum = (int*)alloc(256 * 4);
  float2* pairs = (float2*)alloc(1024 * 8);
  float* scal = (float*)alloc(64);
  if ((size_t)(p - (char*)d_ws) > ws_size) return;  // insufficient workspace

  u16* y1b = (u16*)d_out;  // layer-1 bf16 output staged in d_out bytes (fc2-only reader;
                           // overwritten by final fp32 result in segB<0>)

  // histograms (one launch) + merged scans (+ deg reduction as y=2)
  k_hpart2<<<dim3(HBC, 9), 256, 0, stream>>>(in_dst, has_dst, in_src, partial);
  int nbM = (M + 1023) / 1024, nbN = (N + 1023) / 1024;
  k_scan1d<<<dim3(nbN, 3), 256, 0, stream>>>(partial, M, N, off_in, off_has, deg, bsum);
  k_scan2d<<<2, 256, 0, stream>>>(bsum, nbM, nbN);
  k_scan3d<<<dim3(512, 2), 256, 0, stream>>>(off_in, off_has, bsum, M, N);

  // scatter v3 (atomic-free partition), directions merged via blockIdx.y
  k_coarse<<<PBLK, 256, 0, stream>>>(in_dst, has_dst, bb_in, bb_has);
  k_colscan2<<<dim3(NBK_HAS, 2), 256, 0, stream>>>(bb_in, off_in, bb_has, off_has);
  k_stage2<<<dim3(PBLK, 2), 256, 0, stream>>>(in_dst, in_src, bb_in, ebuf_in, has_dst,
                                              has_src, bb_has, ebuf_has);
  k_place2<<<dim3(NBK_HAS, 2), 256, 0, stream>>>(off_in, ebuf_in, csrc_in, off_has,
                                                 ebuf_has, csrc_has);

  const int FCB = (N + 127) / 128;  // 782 fc blocks = pairs count
  const int SGB = (M + 3) / 4;      // segA blocks
  const int SBB = (N + 3) / 4;      // segB blocks

  auto layer = [&](auto xin, const float* W, const float* b, const float* an_,
                   const float* ae_, auto seg_b) {
    using IT = typename std::remove_const<
        typename std::remove_pointer<decltype(xin)>::type>::type;
    k_fc<IT><<<FCB, 256, 0, stream>>>(xin, W, b, an_, deg, h, na, pairs, N);
    k_smfin<<<1, 256, 0, stream>>>(pairs, FCB, scal);
    k_segA<<<SGB, 256, 0, stream>>>(h, na, scal, csrc_in, off_in, ae_, he, ea, M);
    k_sm2<<<256, 256, 0, stream>>>(ea, na, has_src, has_dst, E, pairs);
    k_smfin<<<1, 256, 0, stream>>>(pairs, 256, scal + 2);
    seg_b();
  };

  layer((const float*)x, W1, b1, an1, ae1, [&] {
    k_segB<1><<<SBB, 256, 0, stream>>>(he, ea, na, scal, csrc_has, off_has, (void*)y1b, N);
  });
  layer((const u16*)y1b, W2, b2, an2, ae2, [&] {
    k_segB<0><<<SBB, 256, 0, stream>>>(he, ea, na, scal, csrc_has, off_has, d_out, N);
  });
}